// Round 3
// baseline (21580.606 us; speedup 1.0000x reference)
//
#include <hip/hip_runtime.h>
#include <math.h>

// Seq2SeqGRU persistent kernel. B=256, T=512, H=512, OUT=10.
// 256 WGs x 384 threads (6 waves). WG = (rowgroup rg of 16 batch rows, 2 hid slices).
// waves 0-1: layer0 (enc) / dec0;  2-3: layer1 gi;  4-5: layer1 gh (+LN/fc duties).
// Weights register-resident (192 VGPR/wave) -> __launch_bounds__(384,1) so the
// compiler gets the full 256-VGPR budget (r2's (384,2) capped at 128 -> spills).
// Cross-WG sync: per-rowgroup device-scope flags. h tiles staged via XOR-swizzled LDS.

#define Hdim 512
#define Bsz  256
#define Tlen 512
#define OUTL 10

typedef _Float16 half8 __attribute__((ext_vector_type(8)));
typedef float    f32x4 __attribute__((ext_vector_type(4)));

__device__ __forceinline__ f32x4 mfma16(half8 a, half8 b, f32x4 c) {
    return __builtin_amdgcn_mfma_f32_16x16x32_f16(a, b, c, 0, 0, 0);
}
__device__ __forceinline__ float sigf(float v) { return 1.0f / (1.0f + __expf(-v)); }

__device__ __forceinline__ void wait_ge(int* f, int target) {
    if (target <= 0) return;
    while (__hip_atomic_load(f, __ATOMIC_RELAXED, __HIP_MEMORY_SCOPE_AGENT) < target)
        __builtin_amdgcn_s_sleep(1);
    __builtin_amdgcn_fence(__ATOMIC_ACQUIRE, "agent");
}
__device__ __forceinline__ void signal(int* f) {
    if ((threadIdx.x & 63) == 0)
        __hip_atomic_fetch_add(f, 1, __ATOMIC_RELEASE, __HIP_MEMORY_SCOPE_AGENT);
}
__device__ __forceinline__ half8 ld_cvt(const float* p) {
    float4 a = *(const float4*)p;
    float4 b = *(const float4*)(p + 4);
    half8 v;
    v[0]=(_Float16)a.x; v[1]=(_Float16)a.y; v[2]=(_Float16)a.z; v[3]=(_Float16)a.w;
    v[4]=(_Float16)b.x; v[5]=(_Float16)b.y; v[6]=(_Float16)b.z; v[7]=(_Float16)b.w;
    return v;
}

// LayerNorm of 16 rows (one wave). In-place on f32, also writes f16 copy.
__device__ void ln_rows(float* hT, _Float16* dst16, const float* gam, const float* bet,
                        int row0, int lane) {
    #pragma unroll 1
    for (int r = 0; r < 16; ++r) {
        float* p = hT + (size_t)(row0 + r) * Hdim;
        float4 v0 = *(const float4*)(p + lane * 8);
        float4 v1 = *(const float4*)(p + lane * 8 + 4);
        float s  = v0.x + v0.y + v0.z + v0.w + v1.x + v1.y + v1.z + v1.w;
        float sq = v0.x*v0.x + v0.y*v0.y + v0.z*v0.z + v0.w*v0.w
                 + v1.x*v1.x + v1.y*v1.y + v1.z*v1.z + v1.w*v1.w;
        #pragma unroll
        for (int m = 1; m < 64; m <<= 1) { s += __shfl_xor(s, m); sq += __shfl_xor(sq, m); }
        float mean = s * (1.0f / Hdim);
        float rstd = rsqrtf(sq * (1.0f / Hdim) - mean * mean + 1e-5f);
        float vv[8] = {v0.x, v0.y, v0.z, v0.w, v1.x, v1.y, v1.z, v1.w};
        _Float16* d = dst16 + (size_t)(row0 + r) * Hdim;
        #pragma unroll
        for (int e = 0; e < 8; ++e) {
            int k = lane * 8 + e;
            float o = (vv[e] - mean) * rstd * gam[k] + bet[k];
            p[k] = o;
            d[k] = (_Float16)o;
        }
    }
}

__global__ __launch_bounds__(384, 1) void gru_all(
    const float* __restrict__ x,
    const float* __restrict__ ewih0, const float* __restrict__ ewhh0,
    const float* __restrict__ ebih0, const float* __restrict__ ebhh0,
    const float* __restrict__ ewih1, const float* __restrict__ ewhh1,
    const float* __restrict__ ebih1, const float* __restrict__ ebhh1,
    const float* __restrict__ lng,   const float* __restrict__ lnb,
    const float* __restrict__ dwih0, const float* __restrict__ dwhh0,
    const float* __restrict__ dbih0, const float* __restrict__ dbhh0,
    const float* __restrict__ dwih1, const float* __restrict__ dwhh1,
    const float* __restrict__ dbih1, const float* __restrict__ dbhh1,
    const float* __restrict__ fcw,   const float* __restrict__ fcb,
    float* __restrict__ out,
    _Float16* h0a, _Float16* h0b, _Float16* h1a, _Float16* h1b,
    float* hT0, float* hT1, float* ybuf, int* flags)
{
    // XOR-swizzled h tiles: half index = row*512 + ((slot8 ^ (row&7))*8), slot8 = col/8.
    __shared__ _Float16 ldsA[16 * 512];     // h0/y0 tile (16KB)
    __shared__ _Float16 ldsB[16 * 512];     // h1 tile
    __shared__ float    ldsAcc[2][3][272];  // gi->gh handoff, rows padded to 17

    const int tid  = threadIdx.x;
    const int wid  = tid >> 6, lane = tid & 63;
    const int role = wid >> 1;              // 0=L0/dec0, 1=GI, 2=GH
    const int pr   = wid & 1;               // which of the WG's two hid slices
    const int rg   = blockIdx.x & 15, hp = blockIdx.x >> 4;
    const int cv   = lane & 15, kg = lane >> 4;
    const int hs   = hp * 2 + pr;
    const int hid  = hs * 16 + cv;
    const int row0 = rg * 16;
    const int rb   = kg * 4;

    int* f0  = flags + (0 * 16 + rg) * 16;
    int* f1  = flags + (1 * 16 + rg) * 16;
    int* fLN = flags + (2 * 16 + rg) * 16;
    int* fD0 = flags + (3 * 16 + rg) * 16;
    int* fD1 = flags + (4 * 16 + rg) * 16;
    int* fY  = flags + (5 * 16 + rg) * 16;

    _Float16* h0buf[2] = {h0a, h0b};
    _Float16* h1buf[2] = {h1a, h1b};

    // ---- encoder weights -> registers (B-frag: lane cv = weight row(hid), kg*8 = k chunk)
    half8 w0[16], w1[16], w2[16];
    {
        const float* wsP = role == 0 ? ewhh0 : (role == 1 ? ewih1 : ewhh1);
        const float* b0 = wsP + (size_t)hid * Hdim + kg * 8;
        #pragma unroll
        for (int kk = 0; kk < 16; ++kk) {
            w0[kk] = ld_cvt(b0 + kk * 32);
            w1[kk] = ld_cvt(b0 + (size_t)512 * Hdim + kk * 32);
            w2[kk] = ld_cvt(b0 + (size_t)1024 * Hdim + kk * 32);
        }
    }
    float cw_r0 = 0, cw_r1 = 0, cw_z0 = 0, cw_z1 = 0, cw_n0 = 0, cw_n1 = 0;
    float bCr = 0, bCz = 0, bIn = 0, bHn = 0;
    if (role == 0) {
        cw_r0 = ewih0[hid * 2];          cw_r1 = ewih0[hid * 2 + 1];
        cw_z0 = ewih0[(512 + hid) * 2];  cw_z1 = ewih0[(512 + hid) * 2 + 1];
        cw_n0 = ewih0[(1024 + hid) * 2]; cw_n1 = ewih0[(1024 + hid) * 2 + 1];
        bCr = ebih0[hid] + ebhh0[hid];
        bCz = ebih0[512 + hid] + ebhh0[512 + hid];
        bIn = ebih0[1024 + hid]; bHn = ebhh0[1024 + hid];
    } else if (role == 2) {
        bCr = ebih1[hid] + ebhh1[hid];
        bCz = ebih1[512 + hid] + ebhh1[512 + hid];
        bIn = ebih1[1024 + hid]; bHn = ebhh1[1024 + hid];
    }
    float hold[4] = {0.f, 0.f, 0.f, 0.f};   // per-lane fp32 h carry (own (b,hid) cells)

#define STAGE_TILES(S0, S1)                                                    \
    do {                                                                       \
        for (int c = tid; c < 2048; c += 384) {                                \
            int r_ = (c >> 6) & 15, cc_ = c & 63;                              \
            int d_ = r_ * 512 + ((cc_ ^ (r_ & 7)) * 8);                        \
            if (c < 1024) *(half8*)&ldsA[d_] =                                 \
                *(const half8*)((S0) + r_ * Hdim + cc_ * 8);                   \
            else          *(half8*)&ldsB[d_] =                                 \
                *(const half8*)((S1) + r_ * Hdim + cc_ * 8);                   \
        }                                                                      \
    } while (0)

    // A-fragment read from swizzled tile: lane (cv,kg), k-chunk kk.
#define LDS_A(BUF, KK) (*(const half8*)&(BUF)[cv * 512 + ((((KK) * 4 + kg) ^ (cv & 7)) * 8)])

    // ================= encoder: 513 iterations =================
    // iter i: layer0 step i (i<512), layer1 step i-1 (i>=1)
    for (int i = 0; i <= Tlen; ++i) {
        // x prefetch (no flag dependency) - hides L2 latency under the poll
        float2 xv[4];
        if (role == 0 && i < Tlen) {
            #pragma unroll
            for (int jj = 0; jj < 4; ++jj)
                xv[jj] = *(const float2*)(x + ((size_t)(row0 + rb + jj) * Tlen + i) * 2);
        }
        wait_ge(f0, 32 * i);            // h0[i-1] complete
        wait_ge(f1, 32 * (i - 1));      // h1[i-2] complete
        {
            const _Float16* s0 = h0buf[(i - 1) & 1] + (size_t)row0 * Hdim;
            const _Float16* s1 = h1buf[(i - 2) & 1] + (size_t)row0 * Hdim;
            STAGE_TILES(s0, s1);
        }
        __syncthreads();   // B: stage visible
        f32x4 a0 = {0,0,0,0}, a1 = {0,0,0,0}, a2 = {0,0,0,0};
        if (role == 2) {
            if (i >= 1) {
                #pragma unroll
                for (int kk = 0; kk < 16; ++kk) {
                    half8 a = LDS_A(ldsB, kk);
                    a0 = mfma16(a, w0[kk], a0);
                    a1 = mfma16(a, w1[kk], a1);
                    a2 = mfma16(a, w2[kk], a2);
                }
            }
        } else if (role == 0) {
            if (i < Tlen) {
                #pragma unroll
                for (int kk = 0; kk < 16; ++kk) {
                    half8 a = LDS_A(ldsA, kk);
                    a0 = mfma16(a, w0[kk], a0);
                    a1 = mfma16(a, w1[kk], a1);
                    a2 = mfma16(a, w2[kk], a2);
                }
                _Float16* dst = h0buf[i & 1];
                #pragma unroll
                for (int jj = 0; jj < 4; ++jj) {
                    int b = row0 + rb + jj;
                    float x0 = xv[jj].x, x1 = xv[jj].y;
                    float r = sigf(x0 * cw_r0 + x1 * cw_r1 + a0[jj] + bCr);
                    float z = sigf(x0 * cw_z0 + x1 * cw_z1 + a1[jj] + bCz);
                    float n = tanhf(x0 * cw_n0 + x1 * cw_n1 + bIn + r * (a2[jj] + bHn));
                    float hv = (1.0f - z) * n + z * hold[jj];
                    hold[jj] = hv;
                    dst[(size_t)b * Hdim + hid] = (_Float16)hv;
                    if (i == Tlen - 1) hT0[(size_t)b * Hdim + hid] = hv;
                }
                signal(f0);
            }
        } else { // GI: gi = y0[i-1] @ wih1^T
            if (i >= 1) {
                #pragma unroll
                for (int kk = 0; kk < 16; ++kk) {
                    half8 a = LDS_A(ldsA, kk);
                    a0 = mfma16(a, w0[kk], a0);
                    a1 = mfma16(a, w1[kk], a1);
                    a2 = mfma16(a, w2[kk], a2);
                }
                #pragma unroll
                for (int jj = 0; jj < 4; ++jj) {
                    int rr = (rb + jj) * 17 + cv;
                    ldsAcc[pr][0][rr] = a0[jj];
                    ldsAcc[pr][1][rr] = a1[jj];
                    ldsAcc[pr][2][rr] = a2[jj];
                }
            }
        }
        __syncthreads();   // C: ldsAcc visible
        if (role == 2 && i >= 1) {
            _Float16* dst = h1buf[(i - 1) & 1];
            #pragma unroll
            for (int jj = 0; jj < 4; ++jj) {
                int b = row0 + rb + jj;
                int rr = (rb + jj) * 17 + cv;
                float gr = ldsAcc[pr][0][rr];
                float gz = ldsAcc[pr][1][rr];
                float gn = ldsAcc[pr][2][rr];
                float r = sigf(gr + a0[jj] + bCr);
                float z = sigf(gz + a1[jj] + bCz);
                float n = tanhf(gn + bIn + r * (a2[jj] + bHn));
                float hv = (1.0f - z) * n + z * hold[jj];
                hold[jj] = hv;
                dst[(size_t)b * Hdim + hid] = (_Float16)hv;
                if (i == Tlen) hT1[(size_t)b * Hdim + hid] = hv;
            }
            signal(f1);
        }
    }

    // ================= LayerNorm phase =================
    if (hp == 0 && wid == 0) {
        wait_ge(f0, 32 * Tlen);
        wait_ge(f1, 32 * Tlen);           // ensure all consumers of h0[511] done
        ln_rows(hT0, h0buf[1], lng, lnb, row0, lane);
        if (lane < 16) {
            int b = row0 + lane;
            ybuf[b] = x[((size_t)b * Tlen + (Tlen - 1)) * 2 + 1];
        }
        signal(fLN);
    }
    if (hp == 0 && wid == 4) {
        wait_ge(f1, 32 * Tlen);
        ln_rows(hT1, h1buf[1], lng, lnb, row0, lane);
        signal(fLN);
    }

    // ---- decoder weights -> registers ----
    {
        const float* wsP = role == 0 ? dwhh0 : (role == 1 ? dwih1 : dwhh1);
        const float* b0 = wsP + (size_t)hid * Hdim + kg * 8;
        #pragma unroll
        for (int kk = 0; kk < 16; ++kk) {
            w0[kk] = ld_cvt(b0 + kk * 32);
            w1[kk] = ld_cvt(b0 + (size_t)512 * Hdim + kk * 32);
            w2[kk] = ld_cvt(b0 + (size_t)1024 * Hdim + kk * 32);
        }
    }
    if (role == 0) {
        cw_r0 = dwih0[hid]; cw_z0 = dwih0[512 + hid]; cw_n0 = dwih0[1024 + hid];
        bCr = dbih0[hid] + dbhh0[hid];
        bCz = dbih0[512 + hid] + dbhh0[512 + hid];
        bIn = dbih0[1024 + hid]; bHn = dbhh0[1024 + hid];
    } else if (role == 2) {
        bCr = dbih1[hid] + dbhh1[hid];
        bCz = dbih1[512 + hid] + dbhh1[512 + hid];
        bIn = dbih1[1024 + hid]; bHn = dbhh1[1024 + hid];
    }
    float fw[8] = {0,0,0,0,0,0,0,0};
    float fb = 0.f;
    const bool is_fc = (hp == 0 && wid == 4);
    if (is_fc) {
        #pragma unroll
        for (int e = 0; e < 8; ++e) fw[e] = fcw[lane * 8 + e];
        fb = fcb[0];
    }
    wait_ge(fLN, 2);
    if (role == 0) {
        #pragma unroll
        for (int jj = 0; jj < 4; ++jj)
            hold[jj] = hT0[(size_t)(row0 + rb + jj) * Hdim + hid];
    } else if (role == 2) {
        #pragma unroll
        for (int jj = 0; jj < 4; ++jj)
            hold[jj] = hT1[(size_t)(row0 + rb + jj) * Hdim + hid];
    }

    // ================= decoder: 10 full steps =================
    for (int t = 0; t < OUTL; ++t) {
        wait_ge(fD0, 32 * t);
        wait_ge(fD1, 32 * t);
        if (role == 0) wait_ge(fY, t);
        {
            const _Float16* s0 = h0buf[(t - 1) & 1] + (size_t)row0 * Hdim;
            const _Float16* s1 = h1buf[(t - 1) & 1] + (size_t)row0 * Hdim;
            STAGE_TILES(s0, s1);
        }
        __syncthreads();
        f32x4 a0 = {0,0,0,0}, a1 = {0,0,0,0}, a2 = {0,0,0,0};
        if (role == 0) {
            #pragma unroll
            for (int kk = 0; kk < 16; ++kk) {
                half8 a = LDS_A(ldsA, kk);
                a0 = mfma16(a, w0[kk], a0);
                a1 = mfma16(a, w1[kk], a1);
                a2 = mfma16(a, w2[kk], a2);
            }
            _Float16* dst = h0buf[t & 1];
            #pragma unroll
            for (int jj = 0; jj < 4; ++jj) {
                int b = row0 + rb + jj;
                float yv = ybuf[b];
                float r = sigf(yv * cw_r0 + a0[jj] + bCr);
                float z = sigf(yv * cw_z0 + a1[jj] + bCz);
                float n = tanhf(yv * cw_n0 + bIn + r * (a2[jj] + bHn));
                float hv = (1.0f - z) * n + z * hold[jj];
                hold[jj] = hv;
                dst[(size_t)b * Hdim + hid] = (_Float16)hv;
            }
            signal(fD0);
        } else if (role == 1) {
            wait_ge(fD0, 32 * (t + 1));   // h0dec[t] fresh from global
            const _Float16* ag = h0buf[t & 1] + (size_t)(row0 + cv) * Hdim + kg * 8;
            #pragma unroll
            for (int kk = 0; kk < 16; ++kk) {
                half8 a = *(const half8*)(ag + kk * 32);
                a0 = mfma16(a, w0[kk], a0);
                a1 = mfma16(a, w1[kk], a1);
                a2 = mfma16(a, w2[kk], a2);
            }
            #pragma unroll
            for (int jj = 0; jj < 4; ++jj) {
                int rr = (rb + jj) * 17 + cv;
                ldsAcc[pr][0][rr] = a0[jj];
                ldsAcc[pr][1][rr] = a1[jj];
                ldsAcc[pr][2][rr] = a2[jj];
            }
        } else {
            #pragma unroll
            for (int kk = 0; kk < 16; ++kk) {
                half8 a = LDS_A(ldsB, kk);
                a0 = mfma16(a, w0[kk], a0);
                a1 = mfma16(a, w1[kk], a1);
                a2 = mfma16(a, w2[kk], a2);
            }
        }
        __syncthreads();
        if (role == 2) {
            _Float16* dst = h1buf[t & 1];
            #pragma unroll
            for (int jj = 0; jj < 4; ++jj) {
                int b = row0 + rb + jj;
                int rr = (rb + jj) * 17 + cv;
                float gr = ldsAcc[pr][0][rr];
                float gz = ldsAcc[pr][1][rr];
                float gn = ldsAcc[pr][2][rr];
                float r = sigf(gr + a0[jj] + bCr);
                float z = sigf(gz + a1[jj] + bCz);
                float n = tanhf(gn + bIn + r * (a2[jj] + bHn));
                float hv = (1.0f - z) * n + z * hold[jj];
                hold[jj] = hv;
                dst[(size_t)b * Hdim + hid] = (_Float16)hv;
            }
            signal(fD1);
            if (is_fc) {
                wait_ge(fD1, 32 * (t + 1));
                const _Float16* hsrc = h1buf[t & 1];
                #pragma unroll 1
                for (int r2 = 0; r2 < 16; ++r2) {
                    int b = row0 + r2;
                    half8 hv8 = *(const half8*)(hsrc + (size_t)b * Hdim + lane * 8);
                    float pa = 0.f;
                    #pragma unroll
                    for (int e = 0; e < 8; ++e) pa += (float)hv8[e] * fw[e];
                    #pragma unroll
                    for (int m = 1; m < 64; m <<= 1) pa += __shfl_xor(pa, m);
                    if (lane == 0) {
                        float yv2 = pa + fb;
                        ybuf[b] = yv2;
                        out[(size_t)b * OUTL + t] = yv2;
                    }
                }
                signal(fY);
            }
        }
    }
#undef STAGE_TILES
#undef LDS_A
}

extern "C" void kernel_launch(void* const* d_in, const int* in_sizes, int n_in,
                              void* d_out, int out_size, void* d_ws, size_t ws_size,
                              hipStream_t stream)
{
    const float* x     = (const float*)d_in[0];
    const float* ewih0 = (const float*)d_in[1];
    const float* ewhh0 = (const float*)d_in[2];
    const float* ebih0 = (const float*)d_in[3];
    const float* ebhh0 = (const float*)d_in[4];
    const float* ewih1 = (const float*)d_in[5];
    const float* ewhh1 = (const float*)d_in[6];
    const float* ebih1 = (const float*)d_in[7];
    const float* ebhh1 = (const float*)d_in[8];
    const float* lng   = (const float*)d_in[9];
    const float* lnb   = (const float*)d_in[10];
    const float* dwih0 = (const float*)d_in[11];
    const float* dwhh0 = (const float*)d_in[12];
    const float* dbih0 = (const float*)d_in[13];
    const float* dbhh0 = (const float*)d_in[14];
    const float* dwih1 = (const float*)d_in[15];
    const float* dwhh1 = (const float*)d_in[16];
    const float* dbih1 = (const float*)d_in[17];
    const float* dbhh1 = (const float*)d_in[18];
    const float* fcw   = (const float*)d_in[19];
    const float* fcb   = (const float*)d_in[20];
    float* out = (float*)d_out;
    (void)in_sizes; (void)n_in; (void)out_size; (void)ws_size;

    char* ws = (char*)d_ws;
    size_t off = 0;
    auto alloc = [&](size_t bytes) -> void* {
        void* p = ws + off;
        off += (bytes + 255) & ~(size_t)255;
        return p;
    };

    // Layout: [flags][h0a][h0b][h1a][h1b] (all zeroed each call) [hT0][hT1][ybuf]
    int* flags = (int*)alloc(6 * 16 * 16 * sizeof(int));          // 6KB
    const size_t HB = (size_t)Bsz * Hdim;
    _Float16* h0a = (_Float16*)alloc(HB * 2);
    _Float16* h0b = (_Float16*)alloc(HB * 2);
    _Float16* h1a = (_Float16*)alloc(HB * 2);
    _Float16* h1b = (_Float16*)alloc(HB * 2);
    size_t zbytes = off;                                          // ~1.03MB
    float* hT0  = (float*)alloc(HB * 4);
    float* hT1  = (float*)alloc(HB * 4);
    float* ybuf = (float*)alloc(Bsz * 4);

    hipMemsetAsync(d_ws, 0, zbytes, stream);

    gru_all<<<256, 384, 0, stream>>>(
        x, ewih0, ewhh0, ebih0, ebhh0, ewih1, ewhh1, ebih1, ebhh1,
        lng, lnb, dwih0, dwhh0, dbih0, dbhh0, dwih1, dwhh1, dbih1, dbhh1,
        fcw, fcb, out, h0a, h0b, h1a, h1b, hT0, hT1, ybuf, flags);
}

// Round 5
// 7996.317 us; speedup vs baseline: 2.6988x; 2.6988x over previous
//
#include <hip/hip_runtime.h>
#include <math.h>

// Seq2SeqGRU persistent kernel. B=256, T=512, H=512, OUT=10.
// 256 WGs x 384 threads (6 waves). WG = (rowgroup rg of 16 batch rows, hid-part hp).
// waves 0-1: layer0/dec0; 2-3: layer1 gi; 4-5: layer1 gh (+LN/fc duties).
// Weights register/AGPR-resident (loaded once). ALL cross-WG exchange via
// RELAXED AGENT-scope __hip_atomic_* (compiles to plain sc1 accesses, NO
// buffer_wbl2/buffer_inv cache maintenance — r2/r3's 40us/step cost).
// Release = s_waitcnt vmcnt(0) before flag add; acquire = compiler barrier.

#define Hdim 512
#define Bsz  256
#define Tlen 512
#define OUTL 10

typedef _Float16 half8 __attribute__((ext_vector_type(8)));
typedef float    f32x4 __attribute__((ext_vector_type(4)));
typedef unsigned long long u64;

__device__ __forceinline__ f32x4 mfma16(half8 a, half8 b, f32x4 c) {
    return __builtin_amdgcn_mfma_f32_16x16x32_f16(a, b, c, 0, 0, 0);
}
__device__ __forceinline__ float sigf(float v) { return 1.0f / (1.0f + __expf(-v)); }

// ---- coherent access primitives (relaxed, agent scope -> sc1, no fences) ----
__device__ __forceinline__ u64 cld8(const void* p) {
    return __hip_atomic_load((const u64*)p, __ATOMIC_RELAXED, __HIP_MEMORY_SCOPE_AGENT);
}
__device__ __forceinline__ float cld4f(const void* p) {
    return __hip_atomic_load((const float*)p, __ATOMIC_RELAXED, __HIP_MEMORY_SCOPE_AGENT);
}
__device__ __forceinline__ void cst4(void* p, float v) {
    __hip_atomic_store((float*)p, v, __ATOMIC_RELAXED, __HIP_MEMORY_SCOPE_AGENT);
}
__device__ __forceinline__ void cst2(void* p, unsigned short v) {
    __hip_atomic_store((unsigned short*)p, v, __ATOMIC_RELAXED, __HIP_MEMORY_SCOPE_AGENT);
}
__device__ __forceinline__ void csth(void* p, float v) {
    cst2(p, __builtin_bit_cast(unsigned short, (_Float16)v));
}
__device__ __forceinline__ half8 h8(u64 lo, u64 hi) {
    union { u64 u[2]; half8 h; } t; t.u[0] = lo; t.u[1] = hi; return t.h;
}

// signal: drain outstanding (sc1) stores, then relaxed agent atomic add.
__device__ __forceinline__ void sig(int* f) {
    asm volatile("s_waitcnt vmcnt(0)" ::: "memory");
    if ((threadIdx.x & 63) == 0)
        __hip_atomic_fetch_add(f, 1, __ATOMIC_RELAXED, __HIP_MEMORY_SCOPE_AGENT);
}
// wait: relaxed poll + compiler-only barrier (hw needs nothing: all data is sc1).
__device__ __forceinline__ void waitc(int* f, int target) {
    if (target <= 0) return;
    while (__hip_atomic_load(f, __ATOMIC_RELAXED, __HIP_MEMORY_SCOPE_AGENT) < target)
        __builtin_amdgcn_s_sleep(1);
    asm volatile("" ::: "memory");
}

__device__ __forceinline__ half8 ld_cvt(const float* p) {
    float4 a = *(const float4*)p;
    float4 b = *(const float4*)(p + 4);
    half8 v;
    v[0]=(_Float16)a.x; v[1]=(_Float16)a.y; v[2]=(_Float16)a.z; v[3]=(_Float16)a.w;
    v[4]=(_Float16)b.x; v[5]=(_Float16)b.y; v[6]=(_Float16)b.z; v[7]=(_Float16)b.w;
    return v;
}

// LayerNorm of 16 rows (one wave), coherent in/out; writes f32 back + f16 copy.
__device__ void ln_rows_coh(float* hT, _Float16* dst16, const float* gam, const float* bet,
                            int row0, int lane) {
    #pragma unroll 1
    for (int r = 0; r < 16; ++r) {
        float* p = hT + (size_t)(row0 + r) * Hdim;
        float v[8];
        #pragma unroll
        for (int e = 0; e < 4; ++e) {
            union { u64 u; float f[2]; } c;
            c.u = cld8(p + lane * 8 + e * 2);
            v[2*e] = c.f[0]; v[2*e+1] = c.f[1];
        }
        float s = 0.f, sq = 0.f;
        #pragma unroll
        for (int e = 0; e < 8; ++e) { s += v[e]; sq += v[e] * v[e]; }
        #pragma unroll
        for (int m = 1; m < 64; m <<= 1) { s += __shfl_xor(s, m); sq += __shfl_xor(sq, m); }
        float mean = s * (1.0f / Hdim);
        float rstd = rsqrtf(sq * (1.0f / Hdim) - mean * mean + 1e-5f);
        _Float16* d = dst16 + (size_t)(row0 + r) * Hdim;
        #pragma unroll
        for (int e = 0; e < 8; ++e) {
            int k = lane * 8 + e;
            float o = (v[e] - mean) * rstd * gam[k] + bet[k];
            cst4(p + k, o);
            csth(d + k, o);
        }
    }
}

__global__ __launch_bounds__(384, 1) void gru_all(
    const float* __restrict__ x,
    const float* __restrict__ ewih0, const float* __restrict__ ewhh0,
    const float* __restrict__ ebih0, const float* __restrict__ ebhh0,
    const float* __restrict__ ewih1, const float* __restrict__ ewhh1,
    const float* __restrict__ ebih1, const float* __restrict__ ebhh1,
    const float* __restrict__ lng,   const float* __restrict__ lnb,
    const float* __restrict__ dwih0, const float* __restrict__ dwhh0,
    const float* __restrict__ dbih0, const float* __restrict__ dbhh0,
    const float* __restrict__ dwih1, const float* __restrict__ dwhh1,
    const float* __restrict__ dbih1, const float* __restrict__ dbhh1,
    const float* __restrict__ fcw,   const float* __restrict__ fcb,
    float* __restrict__ out,
    _Float16* h0a, _Float16* h0b, _Float16* h1a, _Float16* h1b,
    float* hT0, float* hT1, float* ybuf, int* flags)
{
    // ldsAB: [0,8192) = A tile (h0/y0), [8192,16384) = B tile (h1); XOR-swizzled.
    __shared__ _Float16 ldsAB[16384];
    __shared__ float    ldsAcc[2][3][272];  // gi->gh handoff, rows padded to 17

    const int tid  = threadIdx.x;
    const int wid  = tid >> 6, lane = tid & 63;
    const int role = wid >> 1;              // 0=L0/dec0, 1=GI, 2=GH
    const int pr   = wid & 1;
    const int rg   = blockIdx.x & 15, hp = blockIdx.x >> 4;
    const int cv   = lane & 15, kg = lane >> 4;
    const int hs   = hp * 2 + pr;
    const int hid  = hs * 16 + cv;
    const int row0 = rg * 16;
    const int rb   = kg * 4;

    int* f0  = flags + (0 * 16 + rg) * 16;
    int* f1  = flags + (1 * 16 + rg) * 16;
    int* fLN = flags + (2 * 16 + rg) * 16;
    int* fD0 = flags + (3 * 16 + rg) * 16;
    int* fD1 = flags + (4 * 16 + rg) * 16;
    int* fY  = flags + (5 * 16 + rg) * 16;

    _Float16* h0buf[2] = {h0a, h0b};
    _Float16* h1buf[2] = {h1a, h1b};

    // ---- encoder weights -> registers/AGPRs (normal cached loads, read-once) ----
    half8 w0[16], w1[16], w2[16];
    {
        const float* wsP = role == 0 ? ewhh0 : (role == 1 ? ewih1 : ewhh1);
        const float* b0 = wsP + (size_t)hid * Hdim + kg * 8;
        #pragma unroll
        for (int kk = 0; kk < 16; ++kk) {
            w0[kk] = ld_cvt(b0 + kk * 32);
            w1[kk] = ld_cvt(b0 + (size_t)512 * Hdim + kk * 32);
            w2[kk] = ld_cvt(b0 + (size_t)1024 * Hdim + kk * 32);
        }
    }
    float cw_r0 = 0, cw_r1 = 0, cw_z0 = 0, cw_z1 = 0, cw_n0 = 0, cw_n1 = 0;
    float bCr = 0, bCz = 0, bIn = 0, bHn = 0;
    if (role == 0) {
        cw_r0 = ewih0[hid * 2];          cw_r1 = ewih0[hid * 2 + 1];
        cw_z0 = ewih0[(512 + hid) * 2];  cw_z1 = ewih0[(512 + hid) * 2 + 1];
        cw_n0 = ewih0[(1024 + hid) * 2]; cw_n1 = ewih0[(1024 + hid) * 2 + 1];
        bCr = ebih0[hid] + ebhh0[hid];
        bCz = ebih0[512 + hid] + ebhh0[512 + hid];
        bIn = ebih0[1024 + hid]; bHn = ebhh0[1024 + hid];
    } else if (role == 2) {
        bCr = ebih1[hid] + ebhh1[hid];
        bCz = ebih1[512 + hid] + ebhh1[512 + hid];
        bIn = ebih1[1024 + hid]; bHn = ebhh1[1024 + hid];
    }
    float hold[4] = {0.f, 0.f, 0.f, 0.f};

    // Batched coherent stage of both 16x512 f16 tiles: issue all loads, then write LDS.
    // 8B chunk c in [0,4096): tile=c>=2048, row r=(c>>7)&15, q=c&127 (8B col chunk).
#define STAGE_TILES(S0, S1)                                                      \
    do {                                                                         \
        u64 tv_[11]; int dd_[11];                                                \
        _Pragma("unroll")                                                        \
        for (int u_ = 0; u_ < 11; ++u_) {                                        \
            int c_ = tid + u_ * 384;                                             \
            if (c_ < 4096) {                                                     \
                int r_ = (c_ >> 7) & 15, q_ = c_ & 127;                          \
                dd_[u_] = ((c_ < 2048) ? 0 : 8192) + r_ * 512                    \
                          + (((q_ >> 1) ^ (r_ & 7)) * 8) + (q_ & 1) * 4;         \
                tv_[u_] = cld8(((c_ < 2048) ? (S0) : (S1)) + r_ * Hdim + q_ * 4);\
            }                                                                    \
        }                                                                        \
        _Pragma("unroll")                                                        \
        for (int u_ = 0; u_ < 11; ++u_) {                                        \
            int c_ = tid + u_ * 384;                                             \
            if (c_ < 4096) *(u64*)&ldsAB[dd_[u_]] = tv_[u_];                     \
        }                                                                        \
    } while (0)

    // A-fragment read from swizzled tile; BASE 0 = tile A, 8192 = tile B.
#define LDS_A(BASE, KK) \
    (*(const half8*)&ldsAB[(BASE) + cv * 512 + ((((KK) * 4 + kg) ^ (cv & 7)) * 8)])

    // ================= encoder: 513 iterations =================
    // iter i: layer0 step i (i<512), layer1 step i-1 (i>=1)
    for (int i = 0; i <= Tlen; ++i) {
        float2 xv[4];
        if (role == 0 && i < Tlen) {
            #pragma unroll
            for (int jj = 0; jj < 4; ++jj)
                xv[jj] = *(const float2*)(x + ((size_t)(row0 + rb + jj) * Tlen + i) * 2);
        }
        waitc(f0, 32 * i);              // h0[i-1] complete
        waitc(f1, 32 * (i - 1));        // h1[i-2] complete
        {
            const _Float16* s0 = h0buf[(i - 1) & 1] + (size_t)row0 * Hdim;
            const _Float16* s1 = h1buf[(i - 2) & 1] + (size_t)row0 * Hdim;
            STAGE_TILES(s0, s1);
        }
        __syncthreads();   // stage visible
        f32x4 a0 = {0,0,0,0}, a1 = {0,0,0,0}, a2 = {0,0,0,0};
        if (role == 2) {
            if (i >= 1) {
                #pragma unroll
                for (int kk = 0; kk < 16; ++kk) {
                    half8 a = LDS_A(8192, kk);
                    a0 = mfma16(a, w0[kk], a0);
                    a1 = mfma16(a, w1[kk], a1);
                    a2 = mfma16(a, w2[kk], a2);
                }
            }
        } else if (role == 0) {
            if (i < Tlen) {
                #pragma unroll
                for (int kk = 0; kk < 16; ++kk) {
                    half8 a = LDS_A(0, kk);
                    a0 = mfma16(a, w0[kk], a0);
                    a1 = mfma16(a, w1[kk], a1);
                    a2 = mfma16(a, w2[kk], a2);
                }
                _Float16* dst = h0buf[i & 1];
                #pragma unroll
                for (int jj = 0; jj < 4; ++jj) {
                    int b = row0 + rb + jj;
                    float x0 = xv[jj].x, x1 = xv[jj].y;
                    float r = sigf(x0 * cw_r0 + x1 * cw_r1 + a0[jj] + bCr);
                    float z = sigf(x0 * cw_z0 + x1 * cw_z1 + a1[jj] + bCz);
                    float n = tanhf(x0 * cw_n0 + x1 * cw_n1 + bIn + r * (a2[jj] + bHn));
                    float hv = (1.0f - z) * n + z * hold[jj];
                    hold[jj] = hv;
                    csth(dst + (size_t)b * Hdim + hid, hv);
                    if (i == Tlen - 1) cst4(hT0 + (size_t)b * Hdim + hid, hv);
                }
                sig(f0);
            }
        } else { // GI: gi = y0[i-1] @ wih1^T
            if (i >= 1) {
                #pragma unroll
                for (int kk = 0; kk < 16; ++kk) {
                    half8 a = LDS_A(0, kk);
                    a0 = mfma16(a, w0[kk], a0);
                    a1 = mfma16(a, w1[kk], a1);
                    a2 = mfma16(a, w2[kk], a2);
                }
                #pragma unroll
                for (int jj = 0; jj < 4; ++jj) {
                    int rr = (rb + jj) * 17 + cv;
                    ldsAcc[pr][0][rr] = a0[jj];
                    ldsAcc[pr][1][rr] = a1[jj];
                    ldsAcc[pr][2][rr] = a2[jj];
                }
            }
        }
        __syncthreads();   // ldsAcc visible
        if (role == 2 && i >= 1) {
            _Float16* dst = h1buf[(i - 1) & 1];
            #pragma unroll
            for (int jj = 0; jj < 4; ++jj) {
                int b = row0 + rb + jj;
                int rr = (rb + jj) * 17 + cv;
                float gr = ldsAcc[pr][0][rr];
                float gz = ldsAcc[pr][1][rr];
                float gn = ldsAcc[pr][2][rr];
                float r = sigf(gr + a0[jj] + bCr);
                float z = sigf(gz + a1[jj] + bCz);
                float n = tanhf(gn + bIn + r * (a2[jj] + bHn));
                float hv = (1.0f - z) * n + z * hold[jj];
                hold[jj] = hv;
                csth(dst + (size_t)b * Hdim + hid, hv);
                if (i == Tlen) cst4(hT1 + (size_t)b * Hdim + hid, hv);
            }
            sig(f1);
        }
    }

    // ================= LayerNorm =================
    if (hp == 0 && wid == 0) {
        waitc(f0, 32 * Tlen);
        waitc(f1, 32 * Tlen);     // all consumers of h0[511] done staging
        ln_rows_coh(hT0, h0buf[1], lng, lnb, row0, lane);
        if (lane < 16) {
            int b = row0 + lane;
            cst4(ybuf + b, x[((size_t)b * Tlen + (Tlen - 1)) * 2 + 1]);
        }
        sig(fLN);
    }
    if (hp == 0 && wid == 4) {
        waitc(f1, 32 * Tlen);
        ln_rows_coh(hT1, h1buf[1], lng, lnb, row0, lane);
        sig(fLN);
    }

    // ---- decoder weights ----
    {
        const float* wsP = role == 0 ? dwhh0 : (role == 1 ? dwih1 : dwhh1);
        const float* b0 = wsP + (size_t)hid * Hdim + kg * 8;
        #pragma unroll
        for (int kk = 0; kk < 16; ++kk) {
            w0[kk] = ld_cvt(b0 + kk * 32);
            w1[kk] = ld_cvt(b0 + (size_t)512 * Hdim + kk * 32);
            w2[kk] = ld_cvt(b0 + (size_t)1024 * Hdim + kk * 32);
        }
    }
    if (role == 0) {
        cw_r0 = dwih0[hid]; cw_z0 = dwih0[512 + hid]; cw_n0 = dwih0[1024 + hid];
        bCr = dbih0[hid] + dbhh0[hid];
        bCz = dbih0[512 + hid] + dbhh0[512 + hid];
        bIn = dbih0[1024 + hid]; bHn = dbhh0[1024 + hid];
    } else if (role == 2) {
        bCr = dbih1[hid] + dbhh1[hid];
        bCz = dbih1[512 + hid] + dbhh1[512 + hid];
        bIn = dbih1[1024 + hid]; bHn = dbhh1[1024 + hid];
    }
    float fw[8] = {0,0,0,0,0,0,0,0};
    float fb = 0.f;
    const bool is_fc = (hp == 0 && wid == 4);
    if (is_fc) {
        #pragma unroll
        for (int e = 0; e < 8; ++e) fw[e] = fcw[lane * 8 + e];
        fb = fcb[0];
    }
    waitc(fLN, 2);
    if (role == 0 || role == 2) {
        const float* hTsrc = (role == 0) ? hT0 : hT1;
        #pragma unroll
        for (int jj = 0; jj < 4; ++jj)
            hold[jj] = cld4f(hTsrc + (size_t)(row0 + rb + jj) * Hdim + hid);
    }

    // ================= decoder: 10 steps =================
    for (int t = 0; t < OUTL; ++t) {
        waitc(fD0, 32 * t);
        waitc(fD1, 32 * t);
        if (role == 0) waitc(fY, t);
        {
            const _Float16* s0 = h0buf[(t - 1) & 1] + (size_t)row0 * Hdim;
            const _Float16* s1 = h1buf[(t - 1) & 1] + (size_t)row0 * Hdim;
            STAGE_TILES(s0, s1);
        }
        __syncthreads();
        f32x4 a0 = {0,0,0,0}, a1 = {0,0,0,0}, a2 = {0,0,0,0};
        if (role == 0) {
            float yvv[4];
            #pragma unroll
            for (int jj = 0; jj < 4; ++jj) yvv[jj] = cld4f(ybuf + row0 + rb + jj);
            #pragma unroll
            for (int kk = 0; kk < 16; ++kk) {
                half8 a = LDS_A(0, kk);
                a0 = mfma16(a, w0[kk], a0);
                a1 = mfma16(a, w1[kk], a1);
                a2 = mfma16(a, w2[kk], a2);
            }
            _Float16* dst = h0buf[t & 1];
            #pragma unroll
            for (int jj = 0; jj < 4; ++jj) {
                int b = row0 + rb + jj;
                float yv = yvv[jj];
                float r = sigf(yv * cw_r0 + a0[jj] + bCr);
                float z = sigf(yv * cw_z0 + a1[jj] + bCz);
                float n = tanhf(yv * cw_n0 + bIn + r * (a2[jj] + bHn));
                float hv = (1.0f - z) * n + z * hold[jj];
                hold[jj] = hv;
                csth(dst + (size_t)b * Hdim + hid, hv);
            }
            sig(fD0);
        } else if (role == 1) {
            waitc(fD0, 32 * (t + 1));   // fresh h0dec[t]
            const _Float16* ag = h0buf[t & 1] + (size_t)(row0 + cv) * Hdim + kg * 8;
            #pragma unroll
            for (int bt = 0; bt < 4; ++bt) {
                u64 lo0 = cld8(ag + (bt*4+0)*32), hi0 = cld8(ag + (bt*4+0)*32 + 4);
                u64 lo1 = cld8(ag + (bt*4+1)*32), hi1 = cld8(ag + (bt*4+1)*32 + 4);
                u64 lo2 = cld8(ag + (bt*4+2)*32), hi2 = cld8(ag + (bt*4+2)*32 + 4);
                u64 lo3 = cld8(ag + (bt*4+3)*32), hi3 = cld8(ag + (bt*4+3)*32 + 4);
                half8 q0 = h8(lo0, hi0), q1 = h8(lo1, hi1);
                half8 q2 = h8(lo2, hi2), q3 = h8(lo3, hi3);
                a0 = mfma16(q0, w0[bt*4+0], a0); a1 = mfma16(q0, w1[bt*4+0], a1); a2 = mfma16(q0, w2[bt*4+0], a2);
                a0 = mfma16(q1, w0[bt*4+1], a0); a1 = mfma16(q1, w1[bt*4+1], a1); a2 = mfma16(q1, w2[bt*4+1], a2);
                a0 = mfma16(q2, w0[bt*4+2], a0); a1 = mfma16(q2, w1[bt*4+2], a1); a2 = mfma16(q2, w2[bt*4+2], a2);
                a0 = mfma16(q3, w0[bt*4+3], a0); a1 = mfma16(q3, w1[bt*4+3], a1); a2 = mfma16(q3, w2[bt*4+3], a2);
            }
            #pragma unroll
            for (int jj = 0; jj < 4; ++jj) {
                int rr = (rb + jj) * 17 + cv;
                ldsAcc[pr][0][rr] = a0[jj];
                ldsAcc[pr][1][rr] = a1[jj];
                ldsAcc[pr][2][rr] = a2[jj];
            }
        } else {
            #pragma unroll
            for (int kk = 0; kk < 16; ++kk) {
                half8 a = LDS_A(8192, kk);
                a0 = mfma16(a, w0[kk], a0);
                a1 = mfma16(a, w1[kk], a1);
                a2 = mfma16(a, w2[kk], a2);
            }
        }
        __syncthreads();
        if (role == 2) {
            _Float16* dst = h1buf[t & 1];
            #pragma unroll
            for (int jj = 0; jj < 4; ++jj) {
                int b = row0 + rb + jj;
                int rr = (rb + jj) * 17 + cv;
                float gr = ldsAcc[pr][0][rr];
                float gz = ldsAcc[pr][1][rr];
                float gn = ldsAcc[pr][2][rr];
                float r = sigf(gr + a0[jj] + bCr);
                float z = sigf(gz + a1[jj] + bCz);
                float n = tanhf(gn + bIn + r * (a2[jj] + bHn));
                float hv = (1.0f - z) * n + z * hold[jj];
                hold[jj] = hv;
                csth(dst + (size_t)b * Hdim + hid, hv);
            }
            sig(fD1);
            if (is_fc) {
                waitc(fD1, 32 * (t + 1));
                const _Float16* hsrc = h1buf[t & 1];
                #pragma unroll 1
                for (int r2 = 0; r2 < 16; ++r2) {
                    const _Float16* hp8 = hsrc + (size_t)(row0 + r2) * Hdim + lane * 8;
                    half8 hv8 = h8(cld8(hp8), cld8(hp8 + 4));
                    float pa = 0.f;
                    #pragma unroll
                    for (int e = 0; e < 8; ++e) pa += (float)hv8[e] * fw[e];
                    #pragma unroll
                    for (int m = 1; m < 64; m <<= 1) pa += __shfl_xor(pa, m);
                    if (lane == 0) {
                        int b = row0 + r2;
                        float yv2 = pa + fb;
                        cst4(ybuf + b, yv2);
                        out[(size_t)b * OUTL + t] = yv2;
                    }
                }
                sig(fY);
            }
        }
    }
#undef STAGE_TILES
#undef LDS_A
}

extern "C" void kernel_launch(void* const* d_in, const int* in_sizes, int n_in,
                              void* d_out, int out_size, void* d_ws, size_t ws_size,
                              hipStream_t stream)
{
    const float* x     = (const float*)d_in[0];
    const float* ewih0 = (const float*)d_in[1];
    const float* ewhh0 = (const float*)d_in[2];
    const float* ebih0 = (const float*)d_in[3];
    const float* ebhh0 = (const float*)d_in[4];
    const float* ewih1 = (const float*)d_in[5];
    const float* ewhh1 = (const float*)d_in[6];
    const float* ebih1 = (const float*)d_in[7];
    const float* ebhh1 = (const float*)d_in[8];
    const float* lng   = (const float*)d_in[9];
    const float* lnb   = (const float*)d_in[10];
    const float* dwih0 = (const float*)d_in[11];
    const float* dwhh0 = (const float*)d_in[12];
    const float* dbih0 = (const float*)d_in[13];
    const float* dbhh0 = (const float*)d_in[14];
    const float* dwih1 = (const float*)d_in[15];
    const float* dwhh1 = (const float*)d_in[16];
    const float* dbih1 = (const float*)d_in[17];
    const float* dbhh1 = (const float*)d_in[18];
    const float* fcw   = (const float*)d_in[19];
    const float* fcb   = (const float*)d_in[20];
    float* out = (float*)d_out;
    (void)in_sizes; (void)n_in; (void)out_size; (void)ws_size;

    char* ws = (char*)d_ws;
    size_t off = 0;
    auto alloc = [&](size_t bytes) -> void* {
        void* p = ws + off;
        off += (bytes + 255) & ~(size_t)255;
        return p;
    };

    // [flags][h0a][h0b][h1a][h1b] zeroed each call; [hT0][hT1][ybuf] scratch
    int* flags = (int*)alloc(6 * 16 * 16 * sizeof(int));          // 6KB
    const size_t HB = (size_t)Bsz * Hdim;
    _Float16* h0a = (_Float16*)alloc(HB * 2);
    _Float16* h0b = (_Float16*)alloc(HB * 2);
    _Float16* h1a = (_Float16*)alloc(HB * 2);
    _Float16* h1b = (_Float16*)alloc(HB * 2);
    size_t zbytes = off;
    float* hT0  = (float*)alloc(HB * 4);
    float* hT1  = (float*)alloc(HB * 4);
    float* ybuf = (float*)alloc(Bsz * 4);

    hipMemsetAsync(d_ws, 0, zbytes, stream);

    gru_all<<<256, 384, 0, stream>>>(
        x, ewih0, ewhh0, ebih0, ebhh0, ewih1, ewhh1, ebih1, ebhh1,
        lng, lnb, dwih0, dwhh0, dbih0, dbhh0, dwih1, dwhh1, dbih1, dbhh1,
        fcw, fcb, out, h0a, h0b, h1a, h1b, hT0, hT1, ybuf, flags);
}

// Round 6
// 7976.411 us; speedup vs baseline: 2.7056x; 1.0025x over previous
//
#include <hip/hip_runtime.h>
#include <math.h>

// Seq2SeqGRU persistent kernel. B=256, T=512, H=512, OUT=10.
// 256 WGs x 384 threads (6 waves). WG = (rowgroup rg of 16 batch rows, hid-part hp).
// waves 0-1: layer0/dec0; 2-3: layer1 gi; 4-5: layer1 gh (+LN/fc duties).
// Weights register/AGPR-resident. Cross-WG exchange via RELAXED AGENT-scope
// accesses (sc1, no cache-maintenance). r6: flags are per-producer STORE slots
// (32 dwords / 128B line per (kind,rg)) — no atomic RMW, no line ping-pong;
// consumers poll with one wave-wide load + __all.

#define Hdim 512
#define Bsz  256
#define Tlen 512
#define OUTL 10

typedef _Float16 half8 __attribute__((ext_vector_type(8)));
typedef float    f32x4 __attribute__((ext_vector_type(4)));
typedef unsigned long long u64;

__device__ __forceinline__ f32x4 mfma16(half8 a, half8 b, f32x4 c) {
    return __builtin_amdgcn_mfma_f32_16x16x32_f16(a, b, c, 0, 0, 0);
}
__device__ __forceinline__ float sigf(float v) { return 1.0f / (1.0f + __expf(-v)); }

// ---- coherent access primitives (relaxed, agent scope -> sc1, no fences) ----
__device__ __forceinline__ u64 cld8(const void* p) {
    return __hip_atomic_load((const u64*)p, __ATOMIC_RELAXED, __HIP_MEMORY_SCOPE_AGENT);
}
__device__ __forceinline__ float cld4f(const void* p) {
    return __hip_atomic_load((const float*)p, __ATOMIC_RELAXED, __HIP_MEMORY_SCOPE_AGENT);
}
__device__ __forceinline__ void cst4(void* p, float v) {
    __hip_atomic_store((float*)p, v, __ATOMIC_RELAXED, __HIP_MEMORY_SCOPE_AGENT);
}
__device__ __forceinline__ void cst2(void* p, unsigned short v) {
    __hip_atomic_store((unsigned short*)p, v, __ATOMIC_RELAXED, __HIP_MEMORY_SCOPE_AGENT);
}
__device__ __forceinline__ void csth(void* p, float v) {
    cst2(p, __builtin_bit_cast(unsigned short, (_Float16)v));
}
__device__ __forceinline__ half8 h8(u64 lo, u64 hi) {
    union { u64 u[2]; half8 h; } t; t.u[0] = lo; t.u[1] = hi; return t.h;
}

// signal: drain this wave's outstanding (sc1) stores, then STORE val to own slot.
__device__ __forceinline__ void sigS(int* slot, int val) {
    asm volatile("s_waitcnt vmcnt(0)" ::: "memory");
    if ((threadIdx.x & 63) == 0)
        __hip_atomic_store(slot, val, __ATOMIC_RELAXED, __HIP_MEMORY_SCOPE_AGENT);
}
// wait: all NS slots (one 128B line) >= target. One wave-wide load per poll.
template <int NS>
__device__ __forceinline__ void waitN(int* base, int target) {
    if (target <= 0) return;
    int* p = base + ((threadIdx.x & 63) % NS);
    while (true) {
        int v = __hip_atomic_load(p, __ATOMIC_RELAXED, __HIP_MEMORY_SCOPE_AGENT);
        if (__all(v >= target)) break;
        __builtin_amdgcn_s_sleep(1);
    }
    asm volatile("" ::: "memory");
}

__device__ __forceinline__ half8 ld_cvt(const float* p) {
    float4 a = *(const float4*)p;
    float4 b = *(const float4*)(p + 4);
    half8 v;
    v[0]=(_Float16)a.x; v[1]=(_Float16)a.y; v[2]=(_Float16)a.z; v[3]=(_Float16)a.w;
    v[4]=(_Float16)b.x; v[5]=(_Float16)b.y; v[6]=(_Float16)b.z; v[7]=(_Float16)b.w;
    return v;
}

// LayerNorm of 16 rows (one wave), coherent in/out; writes f32 back + f16 copy.
__device__ void ln_rows_coh(float* hT, _Float16* dst16, const float* gam, const float* bet,
                            int row0, int lane) {
    #pragma unroll 1
    for (int r = 0; r < 16; ++r) {
        float* p = hT + (size_t)(row0 + r) * Hdim;
        float v[8];
        #pragma unroll
        for (int e = 0; e < 4; ++e) {
            union { u64 u; float f[2]; } c;
            c.u = cld8(p + lane * 8 + e * 2);
            v[2*e] = c.f[0]; v[2*e+1] = c.f[1];
        }
        float s = 0.f, sq = 0.f;
        #pragma unroll
        for (int e = 0; e < 8; ++e) { s += v[e]; sq += v[e] * v[e]; }
        #pragma unroll
        for (int m = 1; m < 64; m <<= 1) { s += __shfl_xor(s, m); sq += __shfl_xor(sq, m); }
        float mean = s * (1.0f / Hdim);
        float rstd = rsqrtf(sq * (1.0f / Hdim) - mean * mean + 1e-5f);
        _Float16* d = dst16 + (size_t)(row0 + r) * Hdim;
        #pragma unroll
        for (int e = 0; e < 8; ++e) {
            int k = lane * 8 + e;
            float o = (v[e] - mean) * rstd * gam[k] + bet[k];
            cst4(p + k, o);
            csth(d + k, o);
        }
    }
}

__global__ __launch_bounds__(384, 1) void gru_all(
    const float* __restrict__ x,
    const float* __restrict__ ewih0, const float* __restrict__ ewhh0,
    const float* __restrict__ ebih0, const float* __restrict__ ebhh0,
    const float* __restrict__ ewih1, const float* __restrict__ ewhh1,
    const float* __restrict__ ebih1, const float* __restrict__ ebhh1,
    const float* __restrict__ lng,   const float* __restrict__ lnb,
    const float* __restrict__ dwih0, const float* __restrict__ dwhh0,
    const float* __restrict__ dbih0, const float* __restrict__ dbhh0,
    const float* __restrict__ dwih1, const float* __restrict__ dwhh1,
    const float* __restrict__ dbih1, const float* __restrict__ dbhh1,
    const float* __restrict__ fcw,   const float* __restrict__ fcb,
    float* __restrict__ out,
    _Float16* h0a, _Float16* h0b, _Float16* h1a, _Float16* h1b,
    float* hT0, float* hT1, float* ybuf, int* flags)
{
    // ldsAB: [0,8192) = A tile (h0/y0), [8192,16384) = B tile (h1); XOR-swizzled.
    __shared__ _Float16 ldsAB[16384];
    __shared__ float    ldsAcc[2][3][272];  // gi->gh handoff, rows padded to 17

    const int tid  = threadIdx.x;
    const int wid  = tid >> 6, lane = tid & 63;
    const int role = wid >> 1;              // 0=L0/dec0, 1=GI, 2=GH
    const int pr   = wid & 1;
    const int rg   = blockIdx.x & 15, hp = blockIdx.x >> 4;
    const int cv   = lane & 15, kg = lane >> 4;
    const int hs   = hp * 2 + pr;
    const int hid  = hs * 16 + cv;
    const int row0 = rg * 16;
    const int rb   = kg * 4;
    const int slot = hp * 2 + pr;           // producer slot within a flag line

    // flags: (kind*16+rg)*32 dwords; kinds 0=f0 1=f1 2=fD0 3=fD1 4=fLN 5=fY
    int* f0  = flags + (0 * 16 + rg) * 32;
    int* f1  = flags + (1 * 16 + rg) * 32;
    int* fD0 = flags + (2 * 16 + rg) * 32;
    int* fD1 = flags + (3 * 16 + rg) * 32;
    int* fLN = flags + (4 * 16 + rg) * 32;
    int* fY  = flags + (5 * 16 + rg) * 32;

    _Float16* h0buf[2] = {h0a, h0b};
    _Float16* h1buf[2] = {h1a, h1b};

    // ---- encoder weights -> registers/AGPRs (normal cached loads, read-once) ----
    half8 w0[16], w1[16], w2[16];
    {
        const float* wsP = role == 0 ? ewhh0 : (role == 1 ? ewih1 : ewhh1);
        const float* b0 = wsP + (size_t)hid * Hdim + kg * 8;
        #pragma unroll
        for (int kk = 0; kk < 16; ++kk) {
            w0[kk] = ld_cvt(b0 + kk * 32);
            w1[kk] = ld_cvt(b0 + (size_t)512 * Hdim + kk * 32);
            w2[kk] = ld_cvt(b0 + (size_t)1024 * Hdim + kk * 32);
        }
    }
    float cw_r0 = 0, cw_r1 = 0, cw_z0 = 0, cw_z1 = 0, cw_n0 = 0, cw_n1 = 0;
    float bCr = 0, bCz = 0, bIn = 0, bHn = 0;
    if (role == 0) {
        cw_r0 = ewih0[hid * 2];          cw_r1 = ewih0[hid * 2 + 1];
        cw_z0 = ewih0[(512 + hid) * 2];  cw_z1 = ewih0[(512 + hid) * 2 + 1];
        cw_n0 = ewih0[(1024 + hid) * 2]; cw_n1 = ewih0[(1024 + hid) * 2 + 1];
        bCr = ebih0[hid] + ebhh0[hid];
        bCz = ebih0[512 + hid] + ebhh0[512 + hid];
        bIn = ebih0[1024 + hid]; bHn = ebhh0[1024 + hid];
    } else if (role == 2) {
        bCr = ebih1[hid] + ebhh1[hid];
        bCz = ebih1[512 + hid] + ebhh1[512 + hid];
        bIn = ebih1[1024 + hid]; bHn = ebhh1[1024 + hid];
    }
    float hold[4] = {0.f, 0.f, 0.f, 0.f};

    // Batched coherent stage of both 16x512 f16 tiles: issue all loads, then write LDS.
#define STAGE_TILES(S0, S1)                                                      \
    do {                                                                         \
        u64 tv_[11]; int dd_[11];                                                \
        _Pragma("unroll")                                                        \
        for (int u_ = 0; u_ < 11; ++u_) {                                        \
            int c_ = tid + u_ * 384;                                             \
            if (c_ < 4096) {                                                     \
                int r_ = (c_ >> 7) & 15, q_ = c_ & 127;                          \
                dd_[u_] = ((c_ < 2048) ? 0 : 8192) + r_ * 512                    \
                          + (((q_ >> 1) ^ (r_ & 7)) * 8) + (q_ & 1) * 4;         \
                tv_[u_] = cld8(((c_ < 2048) ? (S0) : (S1)) + r_ * Hdim + q_ * 4);\
            }                                                                    \
        }                                                                        \
        _Pragma("unroll")                                                        \
        for (int u_ = 0; u_ < 11; ++u_) {                                        \
            int c_ = tid + u_ * 384;                                             \
            if (c_ < 4096) *(u64*)&ldsAB[dd_[u_]] = tv_[u_];                     \
        }                                                                        \
    } while (0)

#define LDS_A(BASE, KK) \
    (*(const half8*)&ldsAB[(BASE) + cv * 512 + ((((KK) * 4 + kg) ^ (cv & 7)) * 8)])

    // ================= encoder: 513 iterations =================
    // iter i: layer0 step i (i<512), layer1 step i-1 (i>=1)
    for (int i = 0; i <= Tlen; ++i) {
        float2 xv[4];
        if (role == 0 && i < Tlen) {
            #pragma unroll
            for (int jj = 0; jj < 4; ++jj)
                xv[jj] = *(const float2*)(x + ((size_t)(row0 + rb + jj) * Tlen + i) * 2);
        }
        waitN<32>(f0, i);               // h0[i-1] complete (slots store i at iter i-1)
        waitN<32>(f1, i - 1);           // h1[i-2] complete
        {
            const _Float16* s0 = h0buf[(i - 1) & 1] + (size_t)row0 * Hdim;
            const _Float16* s1 = h1buf[(i - 2) & 1] + (size_t)row0 * Hdim;
            STAGE_TILES(s0, s1);
        }
        __syncthreads();   // stage visible
        f32x4 a0 = {0,0,0,0}, a1 = {0,0,0,0}, a2 = {0,0,0,0};
        if (role == 2) {
            if (i >= 1) {
                #pragma unroll
                for (int kk = 0; kk < 16; ++kk) {
                    half8 a = LDS_A(8192, kk);
                    a0 = mfma16(a, w0[kk], a0);
                    a1 = mfma16(a, w1[kk], a1);
                    a2 = mfma16(a, w2[kk], a2);
                }
            }
        } else if (role == 0) {
            if (i < Tlen) {
                #pragma unroll
                for (int kk = 0; kk < 16; ++kk) {
                    half8 a = LDS_A(0, kk);
                    a0 = mfma16(a, w0[kk], a0);
                    a1 = mfma16(a, w1[kk], a1);
                    a2 = mfma16(a, w2[kk], a2);
                }
                _Float16* dst = h0buf[i & 1];
                #pragma unroll
                for (int jj = 0; jj < 4; ++jj) {
                    int b = row0 + rb + jj;
                    float x0 = xv[jj].x, x1 = xv[jj].y;
                    float r = sigf(x0 * cw_r0 + x1 * cw_r1 + a0[jj] + bCr);
                    float z = sigf(x0 * cw_z0 + x1 * cw_z1 + a1[jj] + bCz);
                    float n = tanhf(x0 * cw_n0 + x1 * cw_n1 + bIn + r * (a2[jj] + bHn));
                    float hv = (1.0f - z) * n + z * hold[jj];
                    hold[jj] = hv;
                    csth(dst + (size_t)b * Hdim + hid, hv);
                    if (i == Tlen - 1) cst4(hT0 + (size_t)b * Hdim + hid, hv);
                }
                sigS(f0 + slot, i + 1);
            }
        } else { // GI: gi = y0[i-1] @ wih1^T
            if (i >= 1) {
                #pragma unroll
                for (int kk = 0; kk < 16; ++kk) {
                    half8 a = LDS_A(0, kk);
                    a0 = mfma16(a, w0[kk], a0);
                    a1 = mfma16(a, w1[kk], a1);
                    a2 = mfma16(a, w2[kk], a2);
                }
                #pragma unroll
                for (int jj = 0; jj < 4; ++jj) {
                    int rr = (rb + jj) * 17 + cv;
                    ldsAcc[pr][0][rr] = a0[jj];
                    ldsAcc[pr][1][rr] = a1[jj];
                    ldsAcc[pr][2][rr] = a2[jj];
                }
            }
        }
        __syncthreads();   // ldsAcc visible
        if (role == 2 && i >= 1) {
            _Float16* dst = h1buf[(i - 1) & 1];
            #pragma unroll
            for (int jj = 0; jj < 4; ++jj) {
                int b = row0 + rb + jj;
                int rr = (rb + jj) * 17 + cv;
                float gr = ldsAcc[pr][0][rr];
                float gz = ldsAcc[pr][1][rr];
                float gn = ldsAcc[pr][2][rr];
                float r = sigf(gr + a0[jj] + bCr);
                float z = sigf(gz + a1[jj] + bCz);
                float n = tanhf(gn + bIn + r * (a2[jj] + bHn));
                float hv = (1.0f - z) * n + z * hold[jj];
                hold[jj] = hv;
                csth(dst + (size_t)b * Hdim + hid, hv);
                if (i == Tlen) cst4(hT1 + (size_t)b * Hdim + hid, hv);
            }
            sigS(f1 + slot, i);        // h1[i-1] done
        }
    }

    // ================= LayerNorm =================
    if (hp == 0 && wid == 0) {
        waitN<32>(f0, Tlen);
        waitN<32>(f1, Tlen);      // all WGs past iter-512 staging of h0[511]
        ln_rows_coh(hT0, h0buf[1], lng, lnb, row0, lane);
        if (lane < 16) {
            int b = row0 + lane;
            cst4(ybuf + b, x[((size_t)b * Tlen + (Tlen - 1)) * 2 + 1]);
        }
        sigS(fLN + 0, 1);
    }
    if (hp == 0 && wid == 4) {
        waitN<32>(f1, Tlen);
        ln_rows_coh(hT1, h1buf[1], lng, lnb, row0, lane);
        sigS(fLN + 1, 1);
    }

    // ---- decoder weights ----
    {
        const float* wsP = role == 0 ? dwhh0 : (role == 1 ? dwih1 : dwhh1);
        const float* b0 = wsP + (size_t)hid * Hdim + kg * 8;
        #pragma unroll
        for (int kk = 0; kk < 16; ++kk) {
            w0[kk] = ld_cvt(b0 + kk * 32);
            w1[kk] = ld_cvt(b0 + (size_t)512 * Hdim + kk * 32);
            w2[kk] = ld_cvt(b0 + (size_t)1024 * Hdim + kk * 32);
        }
    }
    if (role == 0) {
        cw_r0 = dwih0[hid]; cw_z0 = dwih0[512 + hid]; cw_n0 = dwih0[1024 + hid];
        bCr = dbih0[hid] + dbhh0[hid];
        bCz = dbih0[512 + hid] + dbhh0[512 + hid];
        bIn = dbih0[1024 + hid]; bHn = dbhh0[1024 + hid];
    } else if (role == 2) {
        bCr = dbih1[hid] + dbhh1[hid];
        bCz = dbih1[512 + hid] + dbhh1[512 + hid];
        bIn = dbih1[1024 + hid]; bHn = dbhh1[1024 + hid];
    }
    float fw[8] = {0,0,0,0,0,0,0,0};
    float fb = 0.f;
    const bool is_fc = (hp == 0 && wid == 4);
    if (is_fc) {
        #pragma unroll
        for (int e = 0; e < 8; ++e) fw[e] = fcw[lane * 8 + e];
        fb = fcb[0];
    }
    waitN<2>(fLN, 1);
    if (role == 0 || role == 2) {
        const float* hTsrc = (role == 0) ? hT0 : hT1;
        #pragma unroll
        for (int jj = 0; jj < 4; ++jj)
            hold[jj] = cld4f(hTsrc + (size_t)(row0 + rb + jj) * Hdim + hid);
    }

    // ================= decoder: 10 steps =================
    for (int t = 0; t < OUTL; ++t) {
        waitN<32>(fD0, t);
        waitN<32>(fD1, t);
        if (role == 0) waitN<1>(fY, t);
        {
            const _Float16* s0 = h0buf[(t - 1) & 1] + (size_t)row0 * Hdim;
            const _Float16* s1 = h1buf[(t - 1) & 1] + (size_t)row0 * Hdim;
            STAGE_TILES(s0, s1);
        }
        __syncthreads();
        f32x4 a0 = {0,0,0,0}, a1 = {0,0,0,0}, a2 = {0,0,0,0};
        if (role == 0) {
            float yvv[4];
            #pragma unroll
            for (int jj = 0; jj < 4; ++jj) yvv[jj] = cld4f(ybuf + row0 + rb + jj);
            #pragma unroll
            for (int kk = 0; kk < 16; ++kk) {
                half8 a = LDS_A(0, kk);
                a0 = mfma16(a, w0[kk], a0);
                a1 = mfma16(a, w1[kk], a1);
                a2 = mfma16(a, w2[kk], a2);
            }
            _Float16* dst = h0buf[t & 1];
            #pragma unroll
            for (int jj = 0; jj < 4; ++jj) {
                int b = row0 + rb + jj;
                float yv = yvv[jj];
                float r = sigf(yv * cw_r0 + a0[jj] + bCr);
                float z = sigf(yv * cw_z0 + a1[jj] + bCz);
                float n = tanhf(yv * cw_n0 + bIn + r * (a2[jj] + bHn));
                float hv = (1.0f - z) * n + z * hold[jj];
                hold[jj] = hv;
                csth(dst + (size_t)b * Hdim + hid, hv);
            }
            sigS(fD0 + slot, t + 1);
        } else if (role == 1) {
            waitN<32>(fD0, t + 1);   // fresh h0dec[t]
            const _Float16* ag = h0buf[t & 1] + (size_t)(row0 + cv) * Hdim + kg * 8;
            #pragma unroll
            for (int bt = 0; bt < 4; ++bt) {
                u64 lo0 = cld8(ag + (bt*4+0)*32), hi0 = cld8(ag + (bt*4+0)*32 + 4);
                u64 lo1 = cld8(ag + (bt*4+1)*32), hi1 = cld8(ag + (bt*4+1)*32 + 4);
                u64 lo2 = cld8(ag + (bt*4+2)*32), hi2 = cld8(ag + (bt*4+2)*32 + 4);
                u64 lo3 = cld8(ag + (bt*4+3)*32), hi3 = cld8(ag + (bt*4+3)*32 + 4);
                half8 q0 = h8(lo0, hi0), q1 = h8(lo1, hi1);
                half8 q2 = h8(lo2, hi2), q3 = h8(lo3, hi3);
                a0 = mfma16(q0, w0[bt*4+0], a0); a1 = mfma16(q0, w1[bt*4+0], a1); a2 = mfma16(q0, w2[bt*4+0], a2);
                a0 = mfma16(q1, w0[bt*4+1], a0); a1 = mfma16(q1, w1[bt*4+1], a1); a2 = mfma16(q1, w2[bt*4+1], a2);
                a0 = mfma16(q2, w0[bt*4+2], a0); a1 = mfma16(q2, w1[bt*4+2], a1); a2 = mfma16(q2, w2[bt*4+2], a2);
                a0 = mfma16(q3, w0[bt*4+3], a0); a1 = mfma16(q3, w1[bt*4+3], a1); a2 = mfma16(q3, w2[bt*4+3], a2);
            }
            #pragma unroll
            for (int jj = 0; jj < 4; ++jj) {
                int rr = (rb + jj) * 17 + cv;
                ldsAcc[pr][0][rr] = a0[jj];
                ldsAcc[pr][1][rr] = a1[jj];
                ldsAcc[pr][2][rr] = a2[jj];
            }
        } else {
            #pragma unroll
            for (int kk = 0; kk < 16; ++kk) {
                half8 a = LDS_A(8192, kk);
                a0 = mfma16(a, w0[kk], a0);
                a1 = mfma16(a, w1[kk], a1);
                a2 = mfma16(a, w2[kk], a2);
            }
        }
        __syncthreads();
        if (role == 2) {
            _Float16* dst = h1buf[t & 1];
            #pragma unroll
            for (int jj = 0; jj < 4; ++jj) {
                int b = row0 + rb + jj;
                int rr = (rb + jj) * 17 + cv;
                float gr = ldsAcc[pr][0][rr];
                float gz = ldsAcc[pr][1][rr];
                float gn = ldsAcc[pr][2][rr];
                float r = sigf(gr + a0[jj] + bCr);
                float z = sigf(gz + a1[jj] + bCz);
                float n = tanhf(gn + bIn + r * (a2[jj] + bHn));
                float hv = (1.0f - z) * n + z * hold[jj];
                hold[jj] = hv;
                csth(dst + (size_t)b * Hdim + hid, hv);
            }
            sigS(fD1 + slot, t + 1);
            if (is_fc) {
                waitN<32>(fD1, t + 1);
                const _Float16* hsrc = h1buf[t & 1];
                #pragma unroll 1
                for (int r2 = 0; r2 < 16; ++r2) {
                    const _Float16* hp8 = hsrc + (size_t)(row0 + r2) * Hdim + lane * 8;
                    half8 hv8 = h8(cld8(hp8), cld8(hp8 + 4));
                    float pa = 0.f;
                    #pragma unroll
                    for (int e = 0; e < 8; ++e) pa += (float)hv8[e] * fw[e];
                    #pragma unroll
                    for (int m = 1; m < 64; m <<= 1) pa += __shfl_xor(pa, m);
                    if (lane == 0) {
                        int b = row0 + r2;
                        float yv2 = pa + fb;
                        cst4(ybuf + b, yv2);
                        out[(size_t)b * OUTL + t] = yv2;
                    }
                }
                sigS(fY, t + 1);
            }
        }
    }
#undef STAGE_TILES
#undef LDS_A
}

extern "C" void kernel_launch(void* const* d_in, const int* in_sizes, int n_in,
                              void* d_out, int out_size, void* d_ws, size_t ws_size,
                              hipStream_t stream)
{
    const float* x     = (const float*)d_in[0];
    const float* ewih0 = (const float*)d_in[1];
    const float* ewhh0 = (const float*)d_in[2];
    const float* ebih0 = (const float*)d_in[3];
    const float* ebhh0 = (const float*)d_in[4];
    const float* ewih1 = (const float*)d_in[5];
    const float* ewhh1 = (const float*)d_in[6];
    const float* ebih1 = (const float*)d_in[7];
    const float* ebhh1 = (const float*)d_in[8];
    const float* lng   = (const float*)d_in[9];
    const float* lnb   = (const float*)d_in[10];
    const float* dwih0 = (const float*)d_in[11];
    const float* dwhh0 = (const float*)d_in[12];
    const float* dbih0 = (const float*)d_in[13];
    const float* dbhh0 = (const float*)d_in[14];
    const float* dwih1 = (const float*)d_in[15];
    const float* dwhh1 = (const float*)d_in[16];
    const float* dbih1 = (const float*)d_in[17];
    const float* dbhh1 = (const float*)d_in[18];
    const float* fcw   = (const float*)d_in[19];
    const float* fcb   = (const float*)d_in[20];
    float* out = (float*)d_out;
    (void)in_sizes; (void)n_in; (void)out_size; (void)ws_size;

    char* ws = (char*)d_ws;
    size_t off = 0;
    auto alloc = [&](size_t bytes) -> void* {
        void* p = ws + off;
        off += (bytes + 255) & ~(size_t)255;
        return p;
    };

    // [flags][h0a][h0b][h1a][h1b] zeroed each call; [hT0][hT1][ybuf] scratch
    int* flags = (int*)alloc(6 * 16 * 32 * sizeof(int));          // 12KB
    const size_t HB = (size_t)Bsz * Hdim;
    _Float16* h0a = (_Float16*)alloc(HB * 2);
    _Float16* h0b = (_Float16*)alloc(HB * 2);
    _Float16* h1a = (_Float16*)alloc(HB * 2);
    _Float16* h1b = (_Float16*)alloc(HB * 2);
    size_t zbytes = off;
    float* hT0  = (float*)alloc(HB * 4);
    float* hT1  = (float*)alloc(HB * 4);
    float* ybuf = (float*)alloc(Bsz * 4);

    hipMemsetAsync(d_ws, 0, zbytes, stream);

    gru_all<<<256, 384, 0, stream>>>(
        x, ewih0, ewhh0, ebih0, ebhh0, ewih1, ewhh1, ebih1, ebhh1,
        lng, lnb, dwih0, dwhh0, dbih0, dbhh0, dwih1, dwhh1, dbih1, dbhh1,
        fcw, fcb, out, h0a, h0b, h1a, h1b, hT0, hT1, ybuf, flags);
}

// Round 7
// 6033.627 us; speedup vs baseline: 3.5767x; 1.3220x over previous
//
#include <hip/hip_runtime.h>
#include <math.h>

// Seq2SeqGRU persistent kernel. B=256, T=512, H=512, OUT=10.
// 256 WGs x 384 threads (6 waves). WG = (rowgroup rg of 16 batch rows, hid-part hp).
// waves 0-1: layer0/dec0; 2-3: layer1 gi; 4-5: layer1 gh (+LN/fc duties).
// Weights register/AGPR-resident. Cross-WG exchange via RELAXED AGENT-scope
// accesses (sc1). r7: h buffers are TILE-MAJOR: h[rg][hs][16x16] f16 — producer
// writes one contiguous 512B tile per wave (full-line stores via LDS repack),
// consumer stages one contiguous 16KB block per rg (fully coalesced 8B loads).
// Kills the r5/r6 scattered-2B-store RMW cost that dominated the step latency.

#define Hdim 512
#define Bsz  256
#define Tlen 512
#define OUTL 10

typedef _Float16 half8 __attribute__((ext_vector_type(8)));
typedef float    f32x4 __attribute__((ext_vector_type(4)));
typedef unsigned long long u64;

__device__ __forceinline__ f32x4 mfma16(half8 a, half8 b, f32x4 c) {
    return __builtin_amdgcn_mfma_f32_16x16x32_f16(a, b, c, 0, 0, 0);
}
__device__ __forceinline__ float sigf(float v) { return 1.0f / (1.0f + __expf(-v)); }

// ---- coherent access primitives (relaxed, agent scope -> sc1, no fences) ----
__device__ __forceinline__ u64 cld8(const void* p) {
    return __hip_atomic_load((const u64*)p, __ATOMIC_RELAXED, __HIP_MEMORY_SCOPE_AGENT);
}
__device__ __forceinline__ float cld4f(const void* p) {
    return __hip_atomic_load((const float*)p, __ATOMIC_RELAXED, __HIP_MEMORY_SCOPE_AGENT);
}
__device__ __forceinline__ void cst8(void* p, u64 v) {
    __hip_atomic_store((u64*)p, v, __ATOMIC_RELAXED, __HIP_MEMORY_SCOPE_AGENT);
}
__device__ __forceinline__ void cst4(void* p, float v) {
    __hip_atomic_store((float*)p, v, __ATOMIC_RELAXED, __HIP_MEMORY_SCOPE_AGENT);
}
__device__ __forceinline__ void cst2(void* p, unsigned short v) {
    __hip_atomic_store((unsigned short*)p, v, __ATOMIC_RELAXED, __HIP_MEMORY_SCOPE_AGENT);
}
__device__ __forceinline__ void csth(void* p, float v) {
    cst2(p, __builtin_bit_cast(unsigned short, (_Float16)v));
}
__device__ __forceinline__ half8 h8(u64 lo, u64 hi) {
    union { u64 u[2]; half8 h; } t; t.u[0] = lo; t.u[1] = hi; return t.h;
}

// signal: drain this wave's outstanding (sc1) stores, then STORE val to own slot.
__device__ __forceinline__ void sigS(int* slot, int val) {
    asm volatile("s_waitcnt vmcnt(0)" ::: "memory");
    if ((threadIdx.x & 63) == 0)
        __hip_atomic_store(slot, val, __ATOMIC_RELAXED, __HIP_MEMORY_SCOPE_AGENT);
}
// wait: all NS slots (one 128B line) >= target. One wave-wide load per poll.
template <int NS>
__device__ __forceinline__ void waitN(int* base, int target) {
    if (target <= 0) return;
    int* p = base + ((threadIdx.x & 63) % NS);
    while (true) {
        int v = __hip_atomic_load(p, __ATOMIC_RELAXED, __HIP_MEMORY_SCOPE_AGENT);
        if (__all(v >= target)) break;
        __builtin_amdgcn_s_sleep(1);
    }
    asm volatile("" ::: "memory");
}

__device__ __forceinline__ half8 ld_cvt(const float* p) {
    float4 a = *(const float4*)p;
    float4 b = *(const float4*)(p + 4);
    half8 v;
    v[0]=(_Float16)a.x; v[1]=(_Float16)a.y; v[2]=(_Float16)a.z; v[3]=(_Float16)a.w;
    v[4]=(_Float16)b.x; v[5]=(_Float16)b.y; v[6]=(_Float16)b.z; v[7]=(_Float16)b.w;
    return v;
}

// LayerNorm of 16 rows (one wave). hT: [b][hid] f32 (in/out). dst16: TILE-MAJOR
// f16 copy at the rg block base (writes tile (k>>4), elem r*16 + (k&15)).
__device__ void ln_rows_coh(float* hT, _Float16* dst16rg, const float* gam, const float* bet,
                            int row0, int lane) {
    #pragma unroll 1
    for (int r = 0; r < 16; ++r) {
        float* p = hT + (size_t)(row0 + r) * Hdim;
        float v[8];
        #pragma unroll
        for (int e = 0; e < 4; ++e) {
            union { u64 u; float f[2]; } c;
            c.u = cld8(p + lane * 8 + e * 2);
            v[2*e] = c.f[0]; v[2*e+1] = c.f[1];
        }
        float s = 0.f, sq = 0.f;
        #pragma unroll
        for (int e = 0; e < 8; ++e) { s += v[e]; sq += v[e] * v[e]; }
        #pragma unroll
        for (int m = 1; m < 64; m <<= 1) { s += __shfl_xor(s, m); sq += __shfl_xor(sq, m); }
        float mean = s * (1.0f / Hdim);
        float rstd = rsqrtf(sq * (1.0f / Hdim) - mean * mean + 1e-5f);
        // lane covers cols lane*8..+7 -> tile (lane>>1), col base (lane&1)*8
        _Float16* d = dst16rg + (lane >> 1) * 256 + r * 16 + (lane & 1) * 8;
        #pragma unroll
        for (int e = 0; e < 8; ++e) {
            int k = lane * 8 + e;
            float o = (v[e] - mean) * rstd * gam[k] + bet[k];
            cst4(p + k, o);
            csth(d + e, o);
        }
    }
}

__global__ __launch_bounds__(384, 1) void gru_all(
    const float* __restrict__ x,
    const float* __restrict__ ewih0, const float* __restrict__ ewhh0,
    const float* __restrict__ ebih0, const float* __restrict__ ebhh0,
    const float* __restrict__ ewih1, const float* __restrict__ ewhh1,
    const float* __restrict__ ebih1, const float* __restrict__ ebhh1,
    const float* __restrict__ lng,   const float* __restrict__ lnb,
    const float* __restrict__ dwih0, const float* __restrict__ dwhh0,
    const float* __restrict__ dbih0, const float* __restrict__ dbhh0,
    const float* __restrict__ dwih1, const float* __restrict__ dwhh1,
    const float* __restrict__ dbih1, const float* __restrict__ dbhh1,
    const float* __restrict__ fcw,   const float* __restrict__ fcb,
    float* __restrict__ out,
    _Float16* h0a, _Float16* h0b, _Float16* h1a, _Float16* h1b,
    float* hT0, float* hT1, float* ybuf, int* flags)
{
    // ldsAB: [0,8192) = A tile block (h0/y0), [8192,16384) = B (h1). LINEAR
    // tile-major (matches global layout; MFMA fragment reads are 16B-contig).
    __shared__ _Float16 ldsAB[16384];
    __shared__ float    ldsAcc[2][3][272];  // gi->gh handoff, rows padded to 17
    __shared__ _Float16 ldsOut[4][256];     // per-wave h-tile repack (roles 0,2)

    const int tid  = threadIdx.x;
    const int wid  = tid >> 6, lane = tid & 63;
    const int role = wid >> 1;              // 0=L0/dec0, 1=GI, 2=GH
    const int pr   = wid & 1;
    const int rg   = blockIdx.x & 15, hp = blockIdx.x >> 4;
    const int cv   = lane & 15, kg = lane >> 4;
    const int hs   = hp * 2 + pr;           // tile index within rg block [0,32)
    const int hid  = hs * 16 + cv;
    const int row0 = rg * 16;
    const int rb   = kg * 4;
    const int slot = hp * 2 + pr;           // producer slot within a flag line
    const int ow   = (role == 0) ? pr : 2 + pr;   // ldsOut slot (roles 0 and 2)
    const size_t rgbase = (size_t)rg * 32 * 256;  // rg block offset in h buffers

    // flags: (kind*16+rg)*32 dwords; kinds 0=f0 1=f1 2=fD0 3=fD1 4=fLN 5=fY
    int* f0  = flags + (0 * 16 + rg) * 32;
    int* f1  = flags + (1 * 16 + rg) * 32;
    int* fD0 = flags + (2 * 16 + rg) * 32;
    int* fD1 = flags + (3 * 16 + rg) * 32;
    int* fLN = flags + (4 * 16 + rg) * 32;
    int* fY  = flags + (5 * 16 + rg) * 32;

    _Float16* h0buf[2] = {h0a, h0b};
    _Float16* h1buf[2] = {h1a, h1b};

    // ---- encoder weights -> registers/AGPRs (normal cached loads, read-once) ----
    half8 w0[16], w1[16], w2[16];
    {
        const float* wsP = role == 0 ? ewhh0 : (role == 1 ? ewih1 : ewhh1);
        const float* b0 = wsP + (size_t)hid * Hdim + kg * 8;
        #pragma unroll
        for (int kk = 0; kk < 16; ++kk) {
            w0[kk] = ld_cvt(b0 + kk * 32);
            w1[kk] = ld_cvt(b0 + (size_t)512 * Hdim + kk * 32);
            w2[kk] = ld_cvt(b0 + (size_t)1024 * Hdim + kk * 32);
        }
    }
    float cw_r0 = 0, cw_r1 = 0, cw_z0 = 0, cw_z1 = 0, cw_n0 = 0, cw_n1 = 0;
    float bCr = 0, bCz = 0, bIn = 0, bHn = 0;
    if (role == 0) {
        cw_r0 = ewih0[hid * 2];          cw_r1 = ewih0[hid * 2 + 1];
        cw_z0 = ewih0[(512 + hid) * 2];  cw_z1 = ewih0[(512 + hid) * 2 + 1];
        cw_n0 = ewih0[(1024 + hid) * 2]; cw_n1 = ewih0[(1024 + hid) * 2 + 1];
        bCr = ebih0[hid] + ebhh0[hid];
        bCz = ebih0[512 + hid] + ebhh0[512 + hid];
        bIn = ebih0[1024 + hid]; bHn = ebhh0[1024 + hid];
    } else if (role == 2) {
        bCr = ebih1[hid] + ebhh1[hid];
        bCz = ebih1[512 + hid] + ebhh1[512 + hid];
        bIn = ebih1[1024 + hid]; bHn = ebhh1[1024 + hid];
    }
    float hold[4] = {0.f, 0.f, 0.f, 0.f};

    // Staging: two contiguous 16KB rg blocks -> LDS linear. B (older dep) loads
    // are issued BEFORE the f0 poll to hide one RTT.
#define STAGE_LOAD(TV, SRC)                                                      \
    do {                                                                         \
        _Pragma("unroll")                                                        \
        for (int u_ = 0; u_ < 6; ++u_) {                                         \
            int c_ = tid + u_ * 384;                                             \
            if (c_ < 2048) (TV)[u_] = cld8((SRC) + c_ * 4);                      \
        }                                                                        \
    } while (0)
#define STAGE_WRITE(TV, LBASE)                                                   \
    do {                                                                         \
        _Pragma("unroll")                                                        \
        for (int u_ = 0; u_ < 6; ++u_) {                                         \
            int c_ = tid + u_ * 384;                                             \
            if (c_ < 2048) *(u64*)&ldsAB[(LBASE) + c_ * 4] = (TV)[u_];           \
        }                                                                        \
    } while (0)

    // A-fragment: element (row cv, k=kk*32+kg*8+e) -> tile 2kk+(kg>>1),
    // offset cv*16 + (kg&1)*8 within tile. 16B contiguous per lane.
#define LDS_A(BASE, KK) \
    (*(const half8*)&ldsAB[(BASE) + (2 * (KK) + (kg >> 1)) * 256 + cv * 16 + (kg & 1) * 8])

    // Epilogue tile repack: per-lane scatter to LDS, then ONE contiguous
    // dwordx2-per-lane coherent store (512B/wave = 8 full lines).
#define STORE_TILE(DSTBUF, HV0, HV1, HV2, HV3)                                   \
    do {                                                                         \
        ldsOut[ow][(rb + 0) * 16 + cv] = (_Float16)(HV0);                        \
        ldsOut[ow][(rb + 1) * 16 + cv] = (_Float16)(HV1);                        \
        ldsOut[ow][(rb + 2) * 16 + cv] = (_Float16)(HV2);                        \
        ldsOut[ow][(rb + 3) * 16 + cv] = (_Float16)(HV3);                        \
        u64 pk_ = *(const u64*)&ldsOut[ow][lane * 4];                            \
        cst8((DSTBUF) + rgbase + (size_t)hs * 256 + lane * 4, pk_);              \
    } while (0)

    // ================= encoder: 513 iterations =================
    // iter i: layer0 step i (i<512), layer1 step i-1 (i>=1)
    for (int i = 0; i <= Tlen; ++i) {
        float2 xv[4];
        if (role == 0 && i < Tlen) {
            #pragma unroll
            for (int jj = 0; jj < 4; ++jj)
                xv[jj] = *(const float2*)(x + ((size_t)(row0 + rb + jj) * Tlen + i) * 2);
        }
        u64 tvB[6], tvA[6];
        waitN<32>(f1, i - 1);           // h1[i-2] complete (older dep first)
        STAGE_LOAD(tvB, h1buf[(i - 2) & 1] + rgbase);
        waitN<32>(f0, i);               // h0[i-1] complete
        STAGE_LOAD(tvA, h0buf[(i - 1) & 1] + rgbase);
        STAGE_WRITE(tvB, 8192);
        STAGE_WRITE(tvA, 0);
        __syncthreads();   // stage visible
        f32x4 a0 = {0,0,0,0}, a1 = {0,0,0,0}, a2 = {0,0,0,0};
        if (role == 2) {
            if (i >= 1) {
                #pragma unroll
                for (int kk = 0; kk < 16; ++kk) {
                    half8 a = LDS_A(8192, kk);
                    a0 = mfma16(a, w0[kk], a0);
                    a1 = mfma16(a, w1[kk], a1);
                    a2 = mfma16(a, w2[kk], a2);
                }
            }
        } else if (role == 0) {
            if (i < Tlen) {
                #pragma unroll
                for (int kk = 0; kk < 16; ++kk) {
                    half8 a = LDS_A(0, kk);
                    a0 = mfma16(a, w0[kk], a0);
                    a1 = mfma16(a, w1[kk], a1);
                    a2 = mfma16(a, w2[kk], a2);
                }
                float hv[4];
                #pragma unroll
                for (int jj = 0; jj < 4; ++jj) {
                    int b = row0 + rb + jj;
                    float x0 = xv[jj].x, x1 = xv[jj].y;
                    float r = sigf(x0 * cw_r0 + x1 * cw_r1 + a0[jj] + bCr);
                    float z = sigf(x0 * cw_z0 + x1 * cw_z1 + a1[jj] + bCz);
                    float n = tanhf(x0 * cw_n0 + x1 * cw_n1 + bIn + r * (a2[jj] + bHn));
                    hv[jj] = (1.0f - z) * n + z * hold[jj];
                    hold[jj] = hv[jj];
                    if (i == Tlen - 1) cst4(hT0 + (size_t)b * Hdim + hid, hv[jj]);
                }
                STORE_TILE(h0buf[i & 1], hv[0], hv[1], hv[2], hv[3]);
                sigS(f0 + slot, i + 1);
            }
        } else { // GI: gi = y0[i-1] @ wih1^T
            if (i >= 1) {
                #pragma unroll
                for (int kk = 0; kk < 16; ++kk) {
                    half8 a = LDS_A(0, kk);
                    a0 = mfma16(a, w0[kk], a0);
                    a1 = mfma16(a, w1[kk], a1);
                    a2 = mfma16(a, w2[kk], a2);
                }
                #pragma unroll
                for (int jj = 0; jj < 4; ++jj) {
                    int rr = (rb + jj) * 17 + cv;
                    ldsAcc[pr][0][rr] = a0[jj];
                    ldsAcc[pr][1][rr] = a1[jj];
                    ldsAcc[pr][2][rr] = a2[jj];
                }
            }
        }
        __syncthreads();   // ldsAcc visible
        if (role == 2 && i >= 1) {
            float hv[4];
            #pragma unroll
            for (int jj = 0; jj < 4; ++jj) {
                int b = row0 + rb + jj;
                int rr = (rb + jj) * 17 + cv;
                float gr = ldsAcc[pr][0][rr];
                float gz = ldsAcc[pr][1][rr];
                float gn = ldsAcc[pr][2][rr];
                float r = sigf(gr + a0[jj] + bCr);
                float z = sigf(gz + a1[jj] + bCz);
                float n = tanhf(gn + bIn + r * (a2[jj] + bHn));
                hv[jj] = (1.0f - z) * n + z * hold[jj];
                hold[jj] = hv[jj];
                if (i == Tlen) cst4(hT1 + (size_t)b * Hdim + hid, hv[jj]);
            }
            STORE_TILE(h1buf[(i - 1) & 1], hv[0], hv[1], hv[2], hv[3]);
            sigS(f1 + slot, i);        // h1[i-1] done
        }
    }

    // ================= LayerNorm =================
    if (hp == 0 && wid == 0) {
        waitN<32>(f0, Tlen);
        waitN<32>(f1, Tlen);      // all WGs past iter-512 staging of h0[511]
        ln_rows_coh(hT0, h0buf[1] + rgbase, lng, lnb, row0, lane);
        if (lane < 16) {
            int b = row0 + lane;
            cst4(ybuf + b, x[((size_t)b * Tlen + (Tlen - 1)) * 2 + 1]);
        }
        sigS(fLN + 0, 1);
    }
    if (hp == 0 && wid == 4) {
        waitN<32>(f1, Tlen);
        ln_rows_coh(hT1, h1buf[1] + rgbase, lng, lnb, row0, lane);
        sigS(fLN + 1, 1);
    }

    // ---- decoder weights ----
    {
        const float* wsP = role == 0 ? dwhh0 : (role == 1 ? dwih1 : dwhh1);
        const float* b0 = wsP + (size_t)hid * Hdim + kg * 8;
        #pragma unroll
        for (int kk = 0; kk < 16; ++kk) {
            w0[kk] = ld_cvt(b0 + kk * 32);
            w1[kk] = ld_cvt(b0 + (size_t)512 * Hdim + kk * 32);
            w2[kk] = ld_cvt(b0 + (size_t)1024 * Hdim + kk * 32);
        }
    }
    if (role == 0) {
        cw_r0 = dwih0[hid]; cw_z0 = dwih0[512 + hid]; cw_n0 = dwih0[1024 + hid];
        bCr = dbih0[hid] + dbhh0[hid];
        bCz = dbih0[512 + hid] + dbhh0[512 + hid];
        bIn = dbih0[1024 + hid]; bHn = dbhh0[1024 + hid];
    } else if (role == 2) {
        bCr = dbih1[hid] + dbhh1[hid];
        bCz = dbih1[512 + hid] + dbhh1[512 + hid];
        bIn = dbih1[1024 + hid]; bHn = dbhh1[1024 + hid];
    }
    float fw[8] = {0,0,0,0,0,0,0,0};
    float fb = 0.f;
    const bool is_fc = (hp == 0 && wid == 4);
    if (is_fc) {
        #pragma unroll
        for (int e = 0; e < 8; ++e) fw[e] = fcw[lane * 8 + e];
        fb = fcb[0];
    }
    waitN<2>(fLN, 1);
    if (role == 0 || role == 2) {
        const float* hTsrc = (role == 0) ? hT0 : hT1;
        #pragma unroll
        for (int jj = 0; jj < 4; ++jj)
            hold[jj] = cld4f(hTsrc + (size_t)(row0 + rb + jj) * Hdim + hid);
    }

    // ================= decoder: 10 steps =================
    for (int t = 0; t < OUTL; ++t) {
        u64 tvB[6], tvA[6];
        waitN<32>(fD1, t);
        STAGE_LOAD(tvB, h1buf[(t - 1) & 1] + rgbase);
        waitN<32>(fD0, t);
        if (role == 0) waitN<1>(fY, t);
        STAGE_LOAD(tvA, h0buf[(t - 1) & 1] + rgbase);
        STAGE_WRITE(tvB, 8192);
        STAGE_WRITE(tvA, 0);
        __syncthreads();
        f32x4 a0 = {0,0,0,0}, a1 = {0,0,0,0}, a2 = {0,0,0,0};
        if (role == 0) {
            float yvv[4];
            #pragma unroll
            for (int jj = 0; jj < 4; ++jj) yvv[jj] = cld4f(ybuf + row0 + rb + jj);
            #pragma unroll
            for (int kk = 0; kk < 16; ++kk) {
                half8 a = LDS_A(0, kk);
                a0 = mfma16(a, w0[kk], a0);
                a1 = mfma16(a, w1[kk], a1);
                a2 = mfma16(a, w2[kk], a2);
            }
            float hv[4];
            #pragma unroll
            for (int jj = 0; jj < 4; ++jj) {
                float yv = yvv[jj];
                float r = sigf(yv * cw_r0 + a0[jj] + bCr);
                float z = sigf(yv * cw_z0 + a1[jj] + bCz);
                float n = tanhf(yv * cw_n0 + bIn + r * (a2[jj] + bHn));
                hv[jj] = (1.0f - z) * n + z * hold[jj];
                hold[jj] = hv[jj];
            }
            STORE_TILE(h0buf[t & 1], hv[0], hv[1], hv[2], hv[3]);
            sigS(fD0 + slot, t + 1);
        } else if (role == 1) {
            waitN<32>(fD0, t + 1);   // fresh h0dec[t]
            const _Float16* agb = h0buf[t & 1] + rgbase;
            #pragma unroll
            for (int kk = 0; kk < 16; ++kk) {
                const _Float16* pa = agb + (2 * kk + (kg >> 1)) * 256 + cv * 16 + (kg & 1) * 8;
                half8 q = h8(cld8(pa), cld8(pa + 4));
                a0 = mfma16(q, w0[kk], a0);
                a1 = mfma16(q, w1[kk], a1);
                a2 = mfma16(q, w2[kk], a2);
            }
            #pragma unroll
            for (int jj = 0; jj < 4; ++jj) {
                int rr = (rb + jj) * 17 + cv;
                ldsAcc[pr][0][rr] = a0[jj];
                ldsAcc[pr][1][rr] = a1[jj];
                ldsAcc[pr][2][rr] = a2[jj];
            }
        } else {
            #pragma unroll
            for (int kk = 0; kk < 16; ++kk) {
                half8 a = LDS_A(8192, kk);
                a0 = mfma16(a, w0[kk], a0);
                a1 = mfma16(a, w1[kk], a1);
                a2 = mfma16(a, w2[kk], a2);
            }
        }
        __syncthreads();
        if (role == 2) {
            float hv[4];
            #pragma unroll
            for (int jj = 0; jj < 4; ++jj) {
                int rr = (rb + jj) * 17 + cv;
                float gr = ldsAcc[pr][0][rr];
                float gz = ldsAcc[pr][1][rr];
                float gn = ldsAcc[pr][2][rr];
                float r = sigf(gr + a0[jj] + bCr);
                float z = sigf(gz + a1[jj] + bCz);
                float n = tanhf(gn + bIn + r * (a2[jj] + bHn));
                hv[jj] = (1.0f - z) * n + z * hold[jj];
                hold[jj] = hv[jj];
            }
            STORE_TILE(h1buf[t & 1], hv[0], hv[1], hv[2], hv[3]);
            sigS(fD1 + slot, t + 1);
            if (is_fc) {
                waitN<32>(fD1, t + 1);
                const _Float16* hb = h1buf[t & 1] + rgbase;
                #pragma unroll 1
                for (int r2 = 0; r2 < 16; ++r2) {
                    const _Float16* hp8 = hb + (lane >> 1) * 256 + r2 * 16 + (lane & 1) * 8;
                    half8 hv8 = h8(cld8(hp8), cld8(hp8 + 4));
                    float pa = 0.f;
                    #pragma unroll
                    for (int e = 0; e < 8; ++e) pa += (float)hv8[e] * fw[e];
                    #pragma unroll
                    for (int m = 1; m < 64; m <<= 1) pa += __shfl_xor(pa, m);
                    if (lane == 0) {
                        int b = row0 + r2;
                        float yv2 = pa + fb;
                        cst4(ybuf + b, yv2);
                        out[(size_t)b * OUTL + t] = yv2;
                    }
                }
                sigS(fY, t + 1);
            }
        }
    }
#undef STAGE_LOAD
#undef STAGE_WRITE
#undef STORE_TILE
#undef LDS_A
}

extern "C" void kernel_launch(void* const* d_in, const int* in_sizes, int n_in,
                              void* d_out, int out_size, void* d_ws, size_t ws_size,
                              hipStream_t stream)
{
    const float* x     = (const float*)d_in[0];
    const float* ewih0 = (const float*)d_in[1];
    const float* ewhh0 = (const float*)d_in[2];
    const float* ebih0 = (const float*)d_in[3];
    const float* ebhh0 = (const float*)d_in[4];
    const float* ewih1 = (const float*)d_in[5];
    const float* ewhh1 = (const float*)d_in[6];
    const float* ebih1 = (const float*)d_in[7];
    const float* ebhh1 = (const float*)d_in[8];
    const float* lng   = (const float*)d_in[9];
    const float* lnb   = (const float*)d_in[10];
    const float* dwih0 = (const float*)d_in[11];
    const float* dwhh0 = (const float*)d_in[12];
    const float* dbih0 = (const float*)d_in[13];
    const float* dbhh0 = (const float*)d_in[14];
    const float* dwih1 = (const float*)d_in[15];
    const float* dwhh1 = (const float*)d_in[16];
    const float* dbih1 = (const float*)d_in[17];
    const float* dbhh1 = (const float*)d_in[18];
    const float* fcw   = (const float*)d_in[19];
    const float* fcb   = (const float*)d_in[20];
    float* out = (float*)d_out;
    (void)in_sizes; (void)n_in; (void)out_size; (void)ws_size;

    char* ws = (char*)d_ws;
    size_t off = 0;
    auto alloc = [&](size_t bytes) -> void* {
        void* p = ws + off;
        off += (bytes + 255) & ~(size_t)255;
        return p;
    };

    // [flags][h0a][h0b][h1a][h1b] zeroed each call; [hT0][hT1][ybuf] scratch
    int* flags = (int*)alloc(6 * 16 * 32 * sizeof(int));          // 12KB
    const size_t HB = (size_t)Bsz * Hdim;
    _Float16* h0a = (_Float16*)alloc(HB * 2);
    _Float16* h0b = (_Float16*)alloc(HB * 2);
    _Float16* h1a = (_Float16*)alloc(HB * 2);
    _Float16* h1b = (_Float16*)alloc(HB * 2);
    size_t zbytes = off;
    float* hT0  = (float*)alloc(HB * 4);
    float* hT1  = (float*)alloc(HB * 4);
    float* ybuf = (float*)alloc(Bsz * 4);

    hipMemsetAsync(d_ws, 0, zbytes, stream);

    gru_all<<<256, 384, 0, stream>>>(
        x, ewih0, ewhh0, ebih0, ebhh0, ewih1, ewhh1, ebih1, ebhh1,
        lng, lnb, dwih0, dwhh0, dbih0, dbhh0, dwih1, dwhh1, dbih1, dbhh1,
        fcw, fcb, out, h0a, h0b, h1a, h1b, hT0, hT1, ybuf, flags);
}